// Round 7
// baseline (535.224 us; speedup 1.0000x reference)
//
#include <hip/hip_runtime.h>
#include <cmath>

typedef unsigned short u16;
typedef __attribute__((ext_vector_type(8))) short short8;
typedef __attribute__((ext_vector_type(4))) float f32x4;
typedef __attribute__((ext_vector_type(4))) u16 u16x4;

// ---------- bf16 helpers ----------
__device__ __forceinline__ float b2f(u16 u) {
    unsigned x = ((unsigned)u) << 16;
    return __builtin_bit_cast(float, x);
}
__device__ __forceinline__ u16 f2b(float f) {
    unsigned x = __builtin_bit_cast(unsigned, f);
    unsigned r = (x + 0x7fffu + ((x >> 16) & 1u)) >> 16;   // RNE
    return (u16)r;
}
// dtype-adaptive load (f32 flag is wave-uniform)
__device__ __forceinline__ float loadx(const void* p, size_t i, int f32) {
    return f32 ? ((const float*)p)[i] : b2f(((const u16*)p)[i]);
}
// async global->LDS, 16B per lane; LDS dest = wave-uniform base + lane*16
__device__ __forceinline__ void gl_lds16(const void* g, void* l) {
    __builtin_amdgcn_global_load_lds(
        (const __attribute__((address_space(1))) void*)g,
        (__attribute__((address_space(3))) void*)l, 16, 0, 0);
}
// fast gelu (tanh form)
__device__ __forceinline__ float gelu_f(float x) {
    float y = 0.7978845608028654f * (x + 0.044715f * x * x * x);
    float e = __expf(2.f * y);
    float t = 1.f - 2.f / (e + 1.f);    // tanh(y)
    return 0.5f * x * (1.f + t);
}

// ---------- problem constants ----------
#define BB 8
#define NN 4096
#define CC 256
#define HH 8
#define DD 32
#define HID 1024
#define MTOK (BB*NN)             // 32768 tokens
#define TOKEL ((size_t)MTOK*CC)  // 8388608 elements per [M,C] tensor
#define TOKELC 8388608

// ws offsets (bytes) — unchanged (112 MiB + 4)
#define WS_INPUT_POS 0u
#define WS_PHIQ   16777216u
#define WS_PHIK   33554432u
#define WS_V      50331648u
#define WS_XLN    67108864u
#define WS_SLN    83886080u
#define WS_OUTPRE 100663296u
#define WS_FLAG   117440512u

// ---------- bf16 weight table (device globals; zero-init BSS) ----------
#define OFF_QKVI  0u
#define OFF_QKVS  196608u
#define OFF_PROJW 393216u
#define OFF_GATEW 458752u
#define OFF_FC1W  589824u
#define OFF_FC2W  851968u
#define OFF_PROJB 1114112u
#define OFF_GATEB 1114368u
#define OFF_FC1B  1114624u
#define OFF_FC2B  1115648u
#define WTOT      1115904u

__device__ __attribute__((aligned(16))) u16 g_wb[WTOT];
__device__ __attribute__((aligned(16))) u16 g_inb[TOKELC];   // bf16 copy of input_
__device__ __attribute__((aligned(16))) u16 g_prevb[TOKELC]; // bf16 copy of prev_state

// =====================================================================
// K0: detect input dtype
// =====================================================================
__global__ __launch_bounds__(64) void detect_kernel(const u16* __restrict__ in0,
                                                    int* __restrict__ flag)
{
    int t = threadIdx.x;
    u16 w = in0[2 * t];
    int e = (w >> 7) & 0xFF;
    int bad = (e < 64 || e > 192) ? 1 : 0;
    unsigned long long m = __ballot(bad);
    if (t == 0) *flag = (__popcll(m) > 8) ? 1 : 0;
}

// =====================================================================
// K0b: convert all GEMM weights + biases to one bf16 table (once)
// =====================================================================
__global__ __launch_bounds__(256) void wconv_kernel(
    const void* qkvi, const void* qkvs, const void* projw, const void* gatew,
    const void* fc1w, const void* fc2w, const void* projb, const void* gateb,
    const void* fc1b, const void* fc2b, const int* __restrict__ flagp)
{
    const int f32 = *flagp;
    unsigned i = blockIdx.x * 256 + threadIdx.x;
    if (i >= WTOT) return;
    const void* src; unsigned off;
    if      (i < OFF_QKVS)  { src = qkvi;  off = OFF_QKVI; }
    else if (i < OFF_PROJW) { src = qkvs;  off = OFF_QKVS; }
    else if (i < OFF_GATEW) { src = projw; off = OFF_PROJW; }
    else if (i < OFF_FC1W)  { src = gatew; off = OFF_GATEW; }
    else if (i < OFF_FC2W)  { src = fc1w;  off = OFF_FC1W; }
    else if (i < OFF_PROJB) { src = fc2w;  off = OFF_FC2W; }
    else if (i < OFF_GATEB) { src = projb; off = OFF_PROJB; }
    else if (i < OFF_FC1B)  { src = gateb; off = OFF_GATEB; }
    else if (i < OFF_FC2B)  { src = fc1b;  off = OFF_FC1B; }
    else                    { src = fc2b;  off = OFF_FC2B; }
    g_wb[i] = f2b(loadx(src, i - off, f32));
}

// =====================================================================
// K1: input_pos = input_+pos ; x_ln = LN1(input_pos) ; s_ln = LN2(prev)
//     + dump bf16 copies of raw input_/prev for the gate GEMM A-operand
// =====================================================================
__global__ __launch_bounds__(256) void prep_kernel(
    const void* __restrict__ inp, const void* __restrict__ prev,
    const void* __restrict__ pos,
    const void* __restrict__ w1, const void* __restrict__ b1,
    const void* __restrict__ w2, const void* __restrict__ b2,
    u16* __restrict__ input_pos, u16* __restrict__ x_ln, u16* __restrict__ s_ln,
    const int* __restrict__ flagp)
{
    const int f32 = *flagp;
    const int m = blockIdx.x;
    const int c = threadIdx.x;
    const int n = m & (NN - 1);
    const size_t idx = (size_t)m * CC + c;

    __shared__ float red[8];

    float inr = loadx(inp, idx, f32);
    float ip = inr + loadx(pos, (size_t)n * CC + c, f32);
    g_inb[idx] = f2b(inr);
    float s = ip, s2 = ip * ip;
    #pragma unroll
    for (int o = 32; o; o >>= 1) { s += __shfl_down(s, o, 64); s2 += __shfl_down(s2, o, 64); }
    if ((threadIdx.x & 63) == 0) { int w6 = threadIdx.x >> 6; red[w6] = s; red[4 + w6] = s2; }
    __syncthreads();
    float mu  = (red[0] + red[1] + red[2] + red[3]) * (1.f / 256.f);
    float var = (red[4] + red[5] + red[6] + red[7]) * (1.f / 256.f) - mu * mu;
    float rs = rsqrtf(var + 1e-5f);
    input_pos[idx] = f2b(ip);
    x_ln[idx] = f2b((ip - mu) * rs * loadx(w1, c, f32) + loadx(b1, c, f32));
    __syncthreads();   // protect red reuse

    float pv = loadx(prev, idx, f32);
    g_prevb[idx] = f2b(pv);
    s = pv; s2 = pv * pv;
    #pragma unroll
    for (int o = 32; o; o >>= 1) { s += __shfl_down(s, o, 64); s2 += __shfl_down(s2, o, 64); }
    if ((threadIdx.x & 63) == 0) { int w6 = threadIdx.x >> 6; red[w6] = s; red[4 + w6] = s2; }
    __syncthreads();
    mu  = (red[0] + red[1] + red[2] + red[3]) * (1.f / 256.f);
    var = (red[4] + red[5] + red[6] + red[7]) * (1.f / 256.f) - mu * mu;
    rs = rsqrtf(var + 1e-5f);
    s_ln[idx] = f2b((pv - mu) * rs * loadx(w2, c, f32) + loadx(b2, c, f32));
}

// =====================================================================
// K7: ln3_out = LN3(output_pre bf16)
// =====================================================================
__global__ __launch_bounds__(256) void ln3_kernel(
    const u16* __restrict__ op, const void* __restrict__ w,
    const void* __restrict__ b, u16* __restrict__ out, const int* __restrict__ flagp)
{
    const int f32 = *flagp;
    const size_t m = blockIdx.x;
    const int c = threadIdx.x;
    const size_t idx = m * CC + c;
    __shared__ float red[8];
    float x = b2f(op[idx]);
    float s = x, s2 = x * x;
    #pragma unroll
    for (int o = 32; o; o >>= 1) { s += __shfl_down(s, o, 64); s2 += __shfl_down(s2, o, 64); }
    if ((threadIdx.x & 63) == 0) { int w6 = threadIdx.x >> 6; red[w6] = s; red[4 + w6] = s2; }
    __syncthreads();
    float mu  = (red[0] + red[1] + red[2] + red[3]) * (1.f / 256.f);
    float var = (red[4] + red[5] + red[6] + red[7]) * (1.f / 256.f) - mu * mu;
    out[idx] = f2b((x - mu) * rsqrtf(var + 1e-5f) * loadx(w, c, f32) + loadx(b, c, f32));
}

// =====================================================================
// K3: kv[bh][d][e] = sum_n phik_t[bh][d][n] * v_t[bh][e][n]
// =====================================================================
__global__ __launch_bounds__(64) void kv_mfma(
    const u16* __restrict__ phik_t, const u16* __restrict__ v_t,
    float* __restrict__ kvout)
{
    const int bh = blockIdx.x;
    const int k0 = blockIdx.y * 256;
    const int lane = threadIdx.x;
    const int quad = lane >> 4, lr = lane & 15;

    const u16* A = phik_t + (size_t)bh * DD * NN;
    const u16* W = v_t    + (size_t)bh * DD * NN;

    f32x4 acc[2][2];
    #pragma unroll
    for (int i = 0; i < 2; ++i)
        #pragma unroll
        for (int j = 0; j < 2; ++j) { f32x4 z = {0.f,0.f,0.f,0.f}; acc[i][j] = z; }

    for (int kk = k0; kk < k0 + 256; kk += 32) {
        short8 a0 = *(const short8*)(A + (size_t)lr * NN + kk + quad * 8);
        short8 a1 = *(const short8*)(A + (size_t)(16 + lr) * NN + kk + quad * 8);
        short8 w0 = *(const short8*)(W + (size_t)lr * NN + kk + quad * 8);
        short8 w1 = *(const short8*)(W + (size_t)(16 + lr) * NN + kk + quad * 8);
        acc[0][0] = __builtin_amdgcn_mfma_f32_16x16x32_bf16(a0, w0, acc[0][0], 0, 0, 0);
        acc[0][1] = __builtin_amdgcn_mfma_f32_16x16x32_bf16(a0, w1, acc[0][1], 0, 0, 0);
        acc[1][0] = __builtin_amdgcn_mfma_f32_16x16x32_bf16(a1, w0, acc[1][0], 0, 0, 0);
        acc[1][1] = __builtin_amdgcn_mfma_f32_16x16x32_bf16(a1, w1, acc[1][1], 0, 0, 0);
    }
    float* base = kvout + (size_t)bh * (DD * DD);
    #pragma unroll
    for (int i = 0; i < 2; ++i)
        #pragma unroll
        for (int j = 0; j < 2; ++j)
            #pragma unroll
            for (int r = 0; r < 4; ++r)
                atomicAdd(base + (i * 16 + quad * 4 + r) * DD + j * 16 + lr, acc[i][j][r]);
}

// =====================================================================
// K4: attn_tok[b,n, h*32+e] = sum_d phiq[b,h,n,d] * kv[b,h][d][e]  (MFMA)
// =====================================================================
__global__ __launch_bounds__(256) void attn_mfma(
    const u16* __restrict__ phiq, const float* __restrict__ kv,
    u16* __restrict__ attn_tok)
{
    const int bh = blockIdx.x;
    const int b = bh >> 3, h = bh & 7;
    const int wv = threadIdx.x >> 6, lane = threadIdx.x & 63;
    const int quad = lane >> 4, lr = lane & 15;

    const float* kvb = kv + (size_t)bh * (DD * DD);
    short8 bf0, bf1;
    #pragma unroll
    for (int j = 0; j < 8; ++j) {
        int d = quad * 8 + j;
        bf0[j] = (short)f2b(kvb[d * DD + lr]);
        bf1[j] = (short)f2b(kvb[d * DD + 16 + lr]);
    }

    const u16* qb = phiq + (size_t)bh * NN * DD;
    const int n0 = blockIdx.y * 512 + wv * 128;
    #pragma unroll
    for (int t = 0; t < 8; ++t) {
        const int nt = n0 + t * 16;
        short8 af = *(const short8*)(qb + (size_t)(nt + lr) * DD + quad * 8);
        f32x4 c0 = {0.f,0.f,0.f,0.f}, c1 = {0.f,0.f,0.f,0.f};
        c0 = __builtin_amdgcn_mfma_f32_16x16x32_bf16(af, bf0, c0, 0, 0, 0);
        c1 = __builtin_amdgcn_mfma_f32_16x16x32_bf16(af, bf1, c1, 0, 0, 0);
        size_t base = ((size_t)b * NN + nt + quad * 4) * CC + h * DD;
        #pragma unroll
        for (int r = 0; r < 4; ++r) {
            attn_tok[base + (size_t)r * CC + lr]      = f2b(c0[r]);
            attn_tok[base + (size_t)r * CC + 16 + lr] = f2b(c1[r]);
        }
    }
}

// =====================================================================
// gemm_direct: barrier-free skinny GEMM for small-N, L2-resident-B GEMMs.
// 256-thread blocks = 4 INDEPENDENT waves; each wave owns a 64x64 output
// tile; A/B fragments loaded DIRECTLY from global (short8), no LDS, no
// barriers -> waves free-run, VMEM latency hidden by TLP + unrolling
// (kv_mfma pattern). B-panels (0.13-0.5 MB) are L2-hot; A-row L2 reuse
// amplification is N/64 <= 16x (well under L2 BW).
// Same swapped-MFMA fragment layout + epilogues as gemm_bt (verified).
// MODE: 1=PROJ 2=GATE 3=FC1 4=FC2
// =====================================================================
template <int MODE>
__global__ __launch_bounds__(256) void gemm_direct(
    const u16* __restrict__ A1in, const u16* __restrict__ A2in,
    int lda, int ldw, int K, int Ksplit, int wcol2,
    u16* __restrict__ o0, u16* __restrict__ o1,
    const u16* __restrict__ xa, const void* __restrict__ xr,
    void* __restrict__ oraw, const int* __restrict__ flagp)
{
    const int f32 = (MODE == 2 || MODE == 4) ? *flagp : 0;

    const u16* W1; const u16* W2; const u16* bias;
    if (MODE == 1)      { W1 = W2 = g_wb + OFF_PROJW; bias = g_wb + OFF_PROJB; }
    else if (MODE == 2) { W1 = W2 = g_wb + OFF_GATEW; bias = g_wb + OFF_GATEB; }
    else if (MODE == 3) { W1 = W2 = g_wb + OFF_FC1W;  bias = g_wb + OFF_FC1B; }
    else                { W1 = W2 = g_wb + OFF_FC2W;  bias = g_wb + OFF_FC2B; }
    const u16* A1 = (MODE == 2) ? g_inb   : A1in;
    const u16* A2 = (MODE == 2) ? g_prevb : A2in;

    // XCD-chunked swizzle (bijective)
    const int gx = gridDim.x;
    const int nwg = gx * (int)gridDim.y;
    const int hw = blockIdx.y * gx + blockIdx.x;
    const int qq = nwg >> 3, rr = nwg & 7;
    const int xc = hw & 7, pp = hw >> 3;
    const int nid = (xc < rr ? xc * (qq + 1) : rr * (qq + 1) + (xc - rr) * qq) + pp;
    const int bx = nid % gx, by = nid / gx;

    const int lane = threadIdx.x & 63;
    const int wv = threadIdx.x >> 6;
    const int quad = lane >> 4, lr = lane & 15;

    const int m0 = by * 256 + wv * 64;    // wave's 64 output rows
    const int n0 = bx * 64;               // wave's 64 output cols

    f32x4 acc[4][4];
    #pragma unroll
    for (int i = 0; i < 4; ++i)
        #pragma unroll
        for (int j = 0; j < 4; ++j) { f32x4 z = {0.f,0.f,0.f,0.f}; acc[i][j] = z; }

    // per-lane row bases (constant over K)
    size_t arow[4], wrow[4];
    #pragma unroll
    for (int i = 0; i < 4; ++i) arow[i] = (size_t)(m0 + i * 16 + lr) * lda + quad * 8;
    #pragma unroll
    for (int j = 0; j < 4; ++j) wrow[j] = (size_t)(n0 + j * 16 + lr) * ldw + quad * 8;

    #pragma unroll 2
    for (int k0 = 0; k0 < K; k0 += 32) {
        const u16* As; const u16* Ws; int ka, kw;
        if (k0 < Ksplit) { As = A1; Ws = W1; ka = k0;          kw = k0; }
        else             { As = A2; Ws = W2; ka = k0 - Ksplit; kw = k0 - Ksplit + wcol2; }
        short8 af[4], bf[4];
        #pragma unroll
        for (int i = 0; i < 4; ++i) af[i] = *(const short8*)(As + arow[i] + ka);
        #pragma unroll
        for (int j = 0; j < 4; ++j) bf[j] = *(const short8*)(Ws + wrow[j] + kw);
        #pragma unroll
        for (int i = 0; i < 4; ++i)
            #pragma unroll
            for (int j = 0; j < 4; ++j)
                acc[i][j] = __builtin_amdgcn_mfma_f32_16x16x32_bf16(bf[j], af[i], acc[i][j], 0, 0, 0);
    }

    constexpr int LDOUT = (MODE == 3) ? HID : CC;
    #pragma unroll
    for (int i = 0; i < 4; ++i) {
        #pragma unroll
        for (int j = 0; j < 4; ++j) {
            const int m = m0 + i * 16 + lr;
            const int c0 = n0 + j * 16 + quad * 4;
            const size_t idx0 = (size_t)m * LDOUT + c0;
            float bias4[4];
            {
                u16x4 t = *(const u16x4*)(bias + c0);
                #pragma unroll
                for (int r = 0; r < 4; ++r) bias4[r] = b2f(t[r]);
            }
            if (MODE == 1) {
                u16x4 xa4 = *(const u16x4*)(xa + idx0);
                u16x4 po, pr;
                #pragma unroll
                for (int r = 0; r < 4; ++r) {
                    float val = acc[i][j][r] + bias4[r];
                    po[r] = f2b(val);                      // attn_proj
                    pr[r] = f2b(b2f(xa4[r]) + val);        // outpre
                }
                *(u16x4*)(o0 + idx0) = po;
                *(u16x4*)(o1 + idx0) = pr;
            } else if (MODE == 2) {
                u16x4 ap4 = *(const u16x4*)(xa + idx0);          // attn_proj
                if (f32) {
                    f32x4 pv = *(const f32x4*)((const float*)xr + idx0);
                    f32x4 o;
                    #pragma unroll
                    for (int r = 0; r < 4; ++r) {
                        float u = 1.f / (1.f + __expf(-(acc[i][j][r] + bias4[r])));
                        o[r] = pv[r] * (1.f - u) + b2f(ap4[r]) * u;
                    }
                    *(f32x4*)((float*)oraw + TOKEL + idx0) = o;
                } else {
                    u16x4 pv = *(const u16x4*)((const u16*)xr + idx0);
                    u16x4 o;
                    #pragma unroll
                    for (int r = 0; r < 4; ++r) {
                        float u = 1.f / (1.f + __expf(-(acc[i][j][r] + bias4[r])));
                        o[r] = f2b(b2f(pv[r]) * (1.f - u) + b2f(ap4[r]) * u);
                    }
                    *(u16x4*)((u16*)oraw + TOKEL + idx0) = o;
                }
            } else if (MODE == 3) {
                u16x4 p;
                #pragma unroll
                for (int r = 0; r < 4; ++r)
                    p[r] = f2b(gelu_f(acc[i][j][r] + bias4[r]));
                *(u16x4*)(o0 + idx0) = p;
            } else {
                u16x4 xa4 = *(const u16x4*)(xa + idx0);
                if (f32) {
                    f32x4 o;
                    #pragma unroll
                    for (int r = 0; r < 4; ++r)
                        o[r] = b2f(xa4[r]) + acc[i][j][r] + bias4[r];
                    *(f32x4*)((float*)oraw + idx0) = o;
                } else {
                    u16x4 o;
                    #pragma unroll
                    for (int r = 0; r < 4; ++r)
                        o[r] = f2b(b2f(xa4[r]) + acc[i][j][r] + bias4[r]);
                    *(u16x4*)((u16*)oraw + idx0) = o;
                }
            }
        }
    }
}

// =====================================================================
// gemm_bt (K2/QKV only): R6 counted-vmcnt triple-buffer pipeline.
// =====================================================================
#define BM 128
#define BN 128
#define BK 32

template <int MODE>
__global__ __launch_bounds__(256) void gemm_bt(
    const u16* __restrict__ A1in, const u16* __restrict__ A2in,
    int lda, int ldw, int K, int Ksplit, int wcol2,
    u16* __restrict__ o0, u16* __restrict__ o1,
    const u16* __restrict__ xa, const void* __restrict__ xr,
    void* __restrict__ oraw, const int* __restrict__ flagp)
{
    __shared__ __attribute__((aligned(16))) u16 ash[3][BM * BK];
    __shared__ __attribute__((aligned(16))) u16 bsh[3][BN * BK];

    const u16* W1; const u16* W2;
    W1 = g_wb + OFF_QKVI; W2 = g_wb + OFF_QKVS;
    const u16* A1 = A1in;
    const u16* A2 = A2in;

    // XCD-chunked tile swizzle
    const int gx = gridDim.x;
    const int nwg = gx * (int)gridDim.y;
    const int hw = blockIdx.y * gx + blockIdx.x;
    const int qq = nwg >> 3, rr = nwg & 7;
    const int xc = hw & 7, pp = hw >> 3;
    const int nid = (xc < rr ? xc * (qq + 1) : rr * (qq + 1) + (xc - rr) * qq) + pp;
    const int bx = nid % gx, by = nid / gx;

    const int tid = threadIdx.x;
    const int lane = tid & 63;
    const int wv = tid >> 6;
    const int wm = wv >> 1, wn = wv & 1;
    const int quad = lane >> 4, lr = lane & 15;

    const bool swp = (bx < 2);

    f32x4 acc[4][4];
    #pragma unroll
    for (int i = 0; i < 4; ++i)
        #pragma unroll
        for (int j = 0; j < 4; ++j) { f32x4 z = {0.f,0.f,0.f,0.f}; acc[i][j] = z; }

    const size_t arow0 = (size_t)by * BM;
    const size_t wrow0 = (size_t)bx * BN;

    const int srow = lane & 31;
    const int sg   = (lane >> 5) << 3;
    const size_t aoff = (arow0 + wv * 32 + srow) * (size_t)lda + sg;
    const size_t woff = (wrow0 + wv * 32 + srow) * (size_t)ldw + sg;

    auto stage = [&](int buf, int k0) {
        const u16* As; const u16* Ws; int ka, kw;
        if (k0 < Ksplit) { As = A1; Ws = W1; ka = k0;          kw = k0; }
        else             { As = A2; Ws = W2; ka = k0 - Ksplit; kw = k0 - Ksplit + wcol2; }
        const u16* ga = As + aoff + ka;
        u16* la = ash[buf] + (wv << 10);
        gl_lds16(ga, la);
        gl_lds16(ga + 16, la + 512);
        const u16* gw = Ws + woff + kw;
        u16* lb = bsh[buf] + (wv << 10);
        gl_lds16(gw, lb);
        gl_lds16(gw + 16, lb + 512);
    };

    auto compute = [&](int buf) {
        short8 af[4], bf[4];
        #pragma unroll
        for (int i = 0; i < 4; ++i) {
            const int ra = wm * 64 + i * 16 + lr;
            af[i] = *(const short8*)(ash[buf] + ((ra >> 5) << 10) + (quad << 8) + ((ra & 31) << 3));
        }
        #pragma unroll
        for (int j = 0; j < 4; ++j) {
            const int rb = wn * 64 + j * 16 + lr;
            bf[j] = *(const short8*)(bsh[buf] + ((rb >> 5) << 10) + (quad << 8) + ((rb & 31) << 3));
        }
        if (swp) {
            #pragma unroll
            for (int i = 0; i < 4; ++i)
                #pragma unroll
                for (int j = 0; j < 4; ++j)
                    acc[i][j] = __builtin_amdgcn_mfma_f32_16x16x32_bf16(bf[j], af[i], acc[i][j], 0, 0, 0);
        } else {
            #pragma unroll
            for (int i = 0; i < 4; ++i)
                #pragma unroll
                for (int j = 0; j < 4; ++j)
                    acc[i][j] = __builtin_amdgcn_mfma_f32_16x16x32_bf16(af[i], bf[j], acc[i][j], 0, 0, 0);
        }
    };

    const int NT = K / BK;
    stage(0, 0);
    stage(1, BK);
    for (int t = 0; t < NT; ++t) {
        if (t + 2 < NT) {
            stage((t + 2) % 3, (t + 2) * BK);
            asm volatile("s_waitcnt vmcnt(8)" ::: "memory");
        } else if (t + 1 < NT) {
            asm volatile("s_waitcnt vmcnt(4)" ::: "memory");
        } else {
            asm volatile("s_waitcnt vmcnt(0)" ::: "memory");
        }
        __builtin_amdgcn_s_barrier();
        asm volatile("" ::: "memory");
        compute(t % 3);
        asm volatile("" ::: "memory");
        __builtin_amdgcn_s_barrier();
    }

    const int mbase = by * BM + wm * 64;
    const int nbase = bx * BN + wn * 64;

    #pragma unroll
    for (int i = 0; i < 4; ++i) {
        #pragma unroll
        for (int j = 0; j < 4; ++j) {
            if (swp) {
                // q third: row=token, cols = 4 consecutive d
                const int m = mbase + i * 16 + lr;
                const int b = m >> 12, n = m & (NN - 1);
                const int c0 = nbase + j * 16 + quad * 4;  // < 256
                const int h = c0 >> 5, d0 = c0 & 31;
                u16x4 p;
                #pragma unroll
                for (int r = 0; r < 4; ++r) {
                    float v = acc[i][j][r];
                    p[r] = f2b((v > 0.f) ? (v + 1.f) : __expf(v));
                }
                *(u16x4*)(o0 + (((size_t)b * HH + h) * NN + n) * DD + d0) = p;
            } else {
                // k/v thirds: unswapped; r traverses tokens -> [B,H,D,N] pack
                const int c = nbase + j * 16 + lr;
                const int which = c >> 8, rem = c & 255, h = rem >> 5, d = rem & 31;
                const int m0 = mbase + i * 16 + quad * 4;
                const int b = m0 >> 12, n0i = m0 & (NN - 1);
                u16x4 p;
                #pragma unroll
                for (int r = 0; r < 4; ++r) {
                    float v = acc[i][j][r];
                    if (which == 1) v = (v > 0.f) ? (v + 1.f) : __expf(v);
                    p[r] = f2b(v);
                }
                u16* dst = o0 + (size_t)which * TOKEL;
                *(u16x4*)(dst + (((size_t)b * HH + h) * DD + d) * NN + n0i) = p;
            }
        }
    }
}

// =====================================================================
extern "C" void kernel_launch(void* const* d_in, const int* in_sizes, int n_in,
                              void* d_out, int out_size, void* d_ws, size_t ws_size,
                              hipStream_t stream)
{
    const void* input_ = d_in[0];
    const void* prev   = d_in[1];
    const void* pos    = d_in[2];
    const void* n1w = d_in[3];  const void* n1b = d_in[4];
    const void* n2w = d_in[5];  const void* n2b = d_in[6];
    const void* n3w = d_in[7];  const void* n3b = d_in[8];
    const void* qkvi = d_in[9]; const void* qkvs = d_in[10];
    const void* projw = d_in[11]; const void* projb = d_in[12];
    const void* gatew = d_in[13]; const void* gateb = d_in[14];
    const void* fc1w = d_in[15]; const void* fc1b = d_in[16];
    const void* fc2w = d_in[17]; const void* fc2b = d_in[18];

    char* ws = (char*)d_ws;
    u16* input_pos = (u16*)(ws + WS_INPUT_POS);
    u16* phiq  = (u16*)(ws + WS_PHIQ);
    u16* phikt = (u16*)(ws + WS_PHIK);
    u16* vt    = (u16*)(ws + WS_V);
    u16* x_ln = (u16*)(ws + WS_XLN);
    u16* s_ln = (u16*)(ws + WS_SLN);
    u16* attn_tok = x_ln;                  // reuse [K4..K5]
    u16* attn_proj = phikt;                // reuse [K5..K6]
    float* kvf = (float*)(ws + WS_SLN);    // reuse [K3..K4]
    u16* ln3o = s_ln;                      // reuse [K7..K8]
    u16* outpre = (u16*)(ws + WS_OUTPRE);
    u16* h1 = (u16*)(ws + WS_INPUT_POS);   // overlays 0..64MiB (dead by K8)
    int* flagp = (int*)(ws + WS_FLAG);

    // K0 dtype detect
    detect_kernel<<<1, 64, 0, stream>>>((const u16*)input_, flagp);
    // K0b convert weights/biases to bf16 table
    wconv_kernel<<<(WTOT + 255) / 256, 256, 0, stream>>>(
        qkvi, qkvs, projw, gatew, fc1w, fc2w, projb, gateb, fc1b, fc2b, flagp);
    // K1 prep (+ bf16 dumps of input_/prev)
    prep_kernel<<<MTOK, 256, 0, stream>>>(input_, prev, pos, n1w, n1b, n2w, n2b,
                                          input_pos, x_ln, s_ln, flagp);
    // K2 qkv: x_ln@qkvi^T + s_ln@qkvs^T, phi fused; q->[B,H,N,D], k/v->[B,H,D,N]
    gemm_bt<0><<<dim3(3 * CC / BN, MTOK / BM), 256, 0, stream>>>(
        x_ln, s_ln, CC, CC, 2 * CC, CC, 0,
        phiq, nullptr, nullptr, nullptr, nullptr, flagp);
    // K3 kv einsum (MFMA split-K + atomics)
    hipMemsetAsync((void*)kvf, 0, BB * HH * DD * DD * sizeof(float), stream);
    kv_mfma<<<dim3(BB * HH, 16), 64, 0, stream>>>(phikt, vt, kvf);
    // K4 attn tokens (MFMA)
    attn_mfma<<<dim3(BB * HH, NN / 512), 256, 0, stream>>>(phiq, kvf, attn_tok);
    // K5 proj (direct): attn_proj ; outpre = input_pos + attn_proj
    gemm_direct<1><<<dim3(CC / 64, MTOK / 256), 256, 0, stream>>>(
        attn_tok, attn_tok, CC, CC, CC, CC, 0,
        attn_proj, outpre, input_pos, nullptr, nullptr, flagp);
    // K6 gate (direct): sigmoid([input_,prev]@gate_w^T+b) -> new_state
    gemm_direct<2><<<dim3(CC / 64, MTOK / 256), 256, 0, stream>>>(
        nullptr, nullptr, CC, 2 * CC, 2 * CC, CC, CC,
        nullptr, nullptr, attn_proj, prev, d_out, flagp);
    // K7 LN3
    ln3_kernel<<<MTOK, 256, 0, stream>>>(outpre, n3w, n3b, ln3o, flagp);
    // K8 fc1 + gelu (direct)
    gemm_direct<3><<<dim3(HID / 64, MTOK / 256), 256, 0, stream>>>(
        ln3o, ln3o, CC, CC, CC, CC, 0,
        h1, nullptr, nullptr, nullptr, nullptr, flagp);
    // K9 fc2 + final residual -> d_out[output] (direct)
    gemm_direct<4><<<dim3(CC / 64, MTOK / 256), 256, 0, stream>>>(
        h1, h1, HID, HID, HID, HID, 0,
        nullptr, nullptr, outpre, nullptr, d_out, flagp);
}

// Round 8
// 517.360 us; speedup vs baseline: 1.0345x; 1.0345x over previous
//
#include <hip/hip_runtime.h>
#include <cmath>

typedef unsigned short u16;
typedef __attribute__((ext_vector_type(8))) short short8;
typedef __attribute__((ext_vector_type(4))) float f32x4;
typedef __attribute__((ext_vector_type(4))) u16 u16x4;

// ---------- bf16 helpers ----------
__device__ __forceinline__ float b2f(u16 u) {
    unsigned x = ((unsigned)u) << 16;
    return __builtin_bit_cast(float, x);
}
__device__ __forceinline__ u16 f2b(float f) {
    unsigned x = __builtin_bit_cast(unsigned, f);
    unsigned r = (x + 0x7fffu + ((x >> 16) & 1u)) >> 16;   // RNE
    return (u16)r;
}
// dtype-adaptive load (f32 flag is wave-uniform)
__device__ __forceinline__ float loadx(const void* p, size_t i, int f32) {
    return f32 ? ((const float*)p)[i] : b2f(((const u16*)p)[i]);
}
// async global->LDS, 16B per lane; LDS dest = wave-uniform base + lane*16
__device__ __forceinline__ void gl_lds16(const void* g, void* l) {
    __builtin_amdgcn_global_load_lds(
        (const __attribute__((address_space(1))) void*)g,
        (__attribute__((address_space(3))) void*)l, 16, 0, 0);
}
// fast gelu (tanh form)
__device__ __forceinline__ float gelu_f(float x) {
    float y = 0.7978845608028654f * (x + 0.044715f * x * x * x);
    float e = __expf(2.f * y);
    float t = 1.f - 2.f / (e + 1.f);    // tanh(y)
    return 0.5f * x * (1.f + t);
}

// ---------- problem constants ----------
#define BB 8
#define NN 4096
#define CC 256
#define HH 8
#define DD 32
#define HID 1024
#define MTOK (BB*NN)             // 32768 tokens
#define TOKEL ((size_t)MTOK*CC)  // 8388608 elements per [M,C] tensor
#define TOKELC 8388608

// ws offsets (bytes) — unchanged (112 MiB + 4)
#define WS_INPUT_POS 0u
#define WS_PHIQ   16777216u
#define WS_PHIK   33554432u
#define WS_V      50331648u
#define WS_XLN    67108864u
#define WS_SLN    83886080u
#define WS_OUTPRE 100663296u
#define WS_FLAG   117440512u

// ---------- bf16 weight table (device globals; zero-init BSS) ----------
#define OFF_QKVI  0u
#define OFF_QKVS  196608u
#define OFF_PROJW 393216u
#define OFF_GATEW 458752u
#define OFF_FC1W  589824u
#define OFF_FC2W  851968u
#define OFF_PROJB 1114112u
#define OFF_GATEB 1114368u
#define OFF_FC1B  1114624u
#define OFF_FC2B  1115648u
#define WTOT      1115904u

__device__ __attribute__((aligned(16))) u16 g_wb[WTOT];
__device__ __attribute__((aligned(16))) u16 g_inb[TOKELC];   // bf16 copy of input_
__device__ __attribute__((aligned(16))) u16 g_prevb[TOKELC]; // bf16 copy of prev_state
__device__ __attribute__((aligned(16))) u16 g_ugate[TOKELC]; // u = sigmoid(gate) bf16

// =====================================================================
// K0: detect input dtype
// =====================================================================
__global__ __launch_bounds__(64) void detect_kernel(const u16* __restrict__ in0,
                                                    int* __restrict__ flag)
{
    int t = threadIdx.x;
    u16 w = in0[2 * t];
    int e = (w >> 7) & 0xFF;
    int bad = (e < 64 || e > 192) ? 1 : 0;
    unsigned long long m = __ballot(bad);
    if (t == 0) *flag = (__popcll(m) > 8) ? 1 : 0;
}

// =====================================================================
// K0b: convert all GEMM weights + biases to one bf16 table (once)
// =====================================================================
__global__ __launch_bounds__(256) void wconv_kernel(
    const void* qkvi, const void* qkvs, const void* projw, const void* gatew,
    const void* fc1w, const void* fc2w, const void* projb, const void* gateb,
    const void* fc1b, const void* fc2b, const int* __restrict__ flagp)
{
    const int f32 = *flagp;
    unsigned i = blockIdx.x * 256 + threadIdx.x;
    if (i >= WTOT) return;
    const void* src; unsigned off;
    if      (i < OFF_QKVS)  { src = qkvi;  off = OFF_QKVI; }
    else if (i < OFF_PROJW) { src = qkvs;  off = OFF_QKVS; }
    else if (i < OFF_GATEW) { src = projw; off = OFF_PROJW; }
    else if (i < OFF_FC1W)  { src = gatew; off = OFF_GATEW; }
    else if (i < OFF_FC2W)  { src = fc1w;  off = OFF_FC1W; }
    else if (i < OFF_PROJB) { src = fc2w;  off = OFF_FC2W; }
    else if (i < OFF_GATEB) { src = projb; off = OFF_PROJB; }
    else if (i < OFF_FC1B)  { src = gateb; off = OFF_GATEB; }
    else if (i < OFF_FC2B)  { src = fc1b;  off = OFF_FC1B; }
    else                    { src = fc2b;  off = OFF_FC2B; }
    g_wb[i] = f2b(loadx(src, i - off, f32));
}

// =====================================================================
// K1: input_pos = input_+pos ; x_ln = LN1(input_pos) ; s_ln = LN2(prev)
//     + dump bf16 copies of raw input_/prev for the fused gate GEMM
// =====================================================================
__global__ __launch_bounds__(256) void prep_kernel(
    const void* __restrict__ inp, const void* __restrict__ prev,
    const void* __restrict__ pos,
    const void* __restrict__ w1, const void* __restrict__ b1,
    const void* __restrict__ w2, const void* __restrict__ b2,
    u16* __restrict__ input_pos, u16* __restrict__ x_ln, u16* __restrict__ s_ln,
    const int* __restrict__ flagp)
{
    const int f32 = *flagp;
    const int m = blockIdx.x;
    const int c = threadIdx.x;
    const int n = m & (NN - 1);
    const size_t idx = (size_t)m * CC + c;

    __shared__ float red[8];

    float inr = loadx(inp, idx, f32);
    float ip = inr + loadx(pos, (size_t)n * CC + c, f32);
    g_inb[idx] = f2b(inr);
    float s = ip, s2 = ip * ip;
    #pragma unroll
    for (int o = 32; o; o >>= 1) { s += __shfl_down(s, o, 64); s2 += __shfl_down(s2, o, 64); }
    if ((threadIdx.x & 63) == 0) { int w6 = threadIdx.x >> 6; red[w6] = s; red[4 + w6] = s2; }
    __syncthreads();
    float mu  = (red[0] + red[1] + red[2] + red[3]) * (1.f / 256.f);
    float var = (red[4] + red[5] + red[6] + red[7]) * (1.f / 256.f) - mu * mu;
    float rs = rsqrtf(var + 1e-5f);
    input_pos[idx] = f2b(ip);
    x_ln[idx] = f2b((ip - mu) * rs * loadx(w1, c, f32) + loadx(b1, c, f32));
    __syncthreads();   // protect red reuse

    float pv = loadx(prev, idx, f32);
    g_prevb[idx] = f2b(pv);
    s = pv; s2 = pv * pv;
    #pragma unroll
    for (int o = 32; o; o >>= 1) { s += __shfl_down(s, o, 64); s2 += __shfl_down(s2, o, 64); }
    if ((threadIdx.x & 63) == 0) { int w6 = threadIdx.x >> 6; red[w6] = s; red[4 + w6] = s2; }
    __syncthreads();
    mu  = (red[0] + red[1] + red[2] + red[3]) * (1.f / 256.f);
    var = (red[4] + red[5] + red[6] + red[7]) * (1.f / 256.f) - mu * mu;
    rs = rsqrtf(var + 1e-5f);
    s_ln[idx] = f2b((pv - mu) * rs * loadx(w2, c, f32) + loadx(b2, c, f32));
}

// =====================================================================
// K7: ln3_out = LN3(output_pre bf16)
// =====================================================================
__global__ __launch_bounds__(256) void ln3_kernel(
    const u16* __restrict__ op, const void* __restrict__ w,
    const void* __restrict__ b, u16* __restrict__ out, const int* __restrict__ flagp)
{
    const int f32 = *flagp;
    const size_t m = blockIdx.x;
    const int c = threadIdx.x;
    const size_t idx = m * CC + c;
    __shared__ float red[8];
    float x = b2f(op[idx]);
    float s = x, s2 = x * x;
    #pragma unroll
    for (int o = 32; o; o >>= 1) { s += __shfl_down(s, o, 64); s2 += __shfl_down(s2, o, 64); }
    if ((threadIdx.x & 63) == 0) { int w6 = threadIdx.x >> 6; red[w6] = s; red[4 + w6] = s2; }
    __syncthreads();
    float mu  = (red[0] + red[1] + red[2] + red[3]) * (1.f / 256.f);
    float var = (red[4] + red[5] + red[6] + red[7]) * (1.f / 256.f) - mu * mu;
    out[idx] = f2b((x - mu) * rsqrtf(var + 1e-5f) * loadx(w, c, f32) + loadx(b, c, f32));
}

// =====================================================================
// K3: kv[bh][d][e] = sum_n phik_t[bh][d][n] * v_t[bh][e][n]
// =====================================================================
__global__ __launch_bounds__(64) void kv_mfma(
    const u16* __restrict__ phik_t, const u16* __restrict__ v_t,
    float* __restrict__ kvout)
{
    const int bh = blockIdx.x;
    const int k0 = blockIdx.y * 256;
    const int lane = threadIdx.x;
    const int quad = lane >> 4, lr = lane & 15;

    const u16* A = phik_t + (size_t)bh * DD * NN;
    const u16* W = v_t    + (size_t)bh * DD * NN;

    f32x4 acc[2][2];
    #pragma unroll
    for (int i = 0; i < 2; ++i)
        #pragma unroll
        for (int j = 0; j < 2; ++j) { f32x4 z = {0.f,0.f,0.f,0.f}; acc[i][j] = z; }

    for (int kk = k0; kk < k0 + 256; kk += 32) {
        short8 a0 = *(const short8*)(A + (size_t)lr * NN + kk + quad * 8);
        short8 a1 = *(const short8*)(A + (size_t)(16 + lr) * NN + kk + quad * 8);
        short8 w0 = *(const short8*)(W + (size_t)lr * NN + kk + quad * 8);
        short8 w1 = *(const short8*)(W + (size_t)(16 + lr) * NN + kk + quad * 8);
        acc[0][0] = __builtin_amdgcn_mfma_f32_16x16x32_bf16(a0, w0, acc[0][0], 0, 0, 0);
        acc[0][1] = __builtin_amdgcn_mfma_f32_16x16x32_bf16(a0, w1, acc[0][1], 0, 0, 0);
        acc[1][0] = __builtin_amdgcn_mfma_f32_16x16x32_bf16(a1, w0, acc[1][0], 0, 0, 0);
        acc[1][1] = __builtin_amdgcn_mfma_f32_16x16x32_bf16(a1, w1, acc[1][1], 0, 0, 0);
    }
    float* base = kvout + (size_t)bh * (DD * DD);
    #pragma unroll
    for (int i = 0; i < 2; ++i)
        #pragma unroll
        for (int j = 0; j < 2; ++j)
            #pragma unroll
            for (int r = 0; r < 4; ++r)
                atomicAdd(base + (i * 16 + quad * 4 + r) * DD + j * 16 + lr, acc[i][j][r]);
}

// =====================================================================
// K4: attn_tok[b,n, h*32+e] = sum_d phiq[b,h,n,d] * kv[b,h][d][e]  (MFMA)
// =====================================================================
__global__ __launch_bounds__(256) void attn_mfma(
    const u16* __restrict__ phiq, const float* __restrict__ kv,
    u16* __restrict__ attn_tok)
{
    const int bh = blockIdx.x;
    const int b = bh >> 3, h = bh & 7;
    const int wv = threadIdx.x >> 6, lane = threadIdx.x & 63;
    const int quad = lane >> 4, lr = lane & 15;

    const float* kvb = kv + (size_t)bh * (DD * DD);
    short8 bf0, bf1;
    #pragma unroll
    for (int j = 0; j < 8; ++j) {
        int d = quad * 8 + j;
        bf0[j] = (short)f2b(kvb[d * DD + lr]);
        bf1[j] = (short)f2b(kvb[d * DD + 16 + lr]);
    }

    const u16* qb = phiq + (size_t)bh * NN * DD;
    const int n0 = blockIdx.y * 512 + wv * 128;
    #pragma unroll
    for (int t = 0; t < 8; ++t) {
        const int nt = n0 + t * 16;
        short8 af = *(const short8*)(qb + (size_t)(nt + lr) * DD + quad * 8);
        f32x4 c0 = {0.f,0.f,0.f,0.f}, c1 = {0.f,0.f,0.f,0.f};
        c0 = __builtin_amdgcn_mfma_f32_16x16x32_bf16(af, bf0, c0, 0, 0, 0);
        c1 = __builtin_amdgcn_mfma_f32_16x16x32_bf16(af, bf1, c1, 0, 0, 0);
        size_t base = ((size_t)b * NN + nt + quad * 4) * CC + h * DD;
        #pragma unroll
        for (int r = 0; r < 4; ++r) {
            attn_tok[base + (size_t)r * CC + lr]      = f2b(c0[r]);
            attn_tok[base + (size_t)r * CC + 16 + lr] = f2b(c1[r]);
        }
    }
}

// =====================================================================
// MFMA GEMM (R6-verified counted-vmcnt triple-buffer loop).
// MODE 0: FUSED qkv+gate. grid x = 8: bx<2 -> q (phi, scatter);
//   bx 2..5 -> k/v transposed pack; bx 6..7 -> GATE columns:
//   A = [g_inb | g_prevb], W = gatew [256 x 512], epilogue stores
//   u = sigmoid(acc + gateb) as bf16 to g_ugate. Gate has no dependency
//   on attention, so its blocks ride K2's dispatch (+33% block supply).
// MODE 1: proj + outpre + NEW_STATE (u from g_ugate, prev raw via xr,
//   attn in f32 regs -> better precision than old K6's bf16 re-read).
// MODE 3: fc1+gelu.  MODE 4: fc2+residual.
// =====================================================================
#define BM 128
#define BN 128
#define BK 32

template <int MODE>
__global__ __launch_bounds__(256) void gemm_bt(
    const u16* __restrict__ A1in, const u16* __restrict__ A2in,
    int lda, int ldw, int K, int Ksplit, int wcol2,
    u16* __restrict__ o0, u16* __restrict__ o1,
    const u16* __restrict__ xa, const void* __restrict__ xr,
    void* __restrict__ oraw, const int* __restrict__ flagp)
{
    __shared__ __attribute__((aligned(16))) u16 ash[3][BM * BK];
    __shared__ __attribute__((aligned(16))) u16 bsh[3][BN * BK];

    const int f32 = (MODE == 1 || MODE == 4) ? *flagp : 0;

    const u16* W1; const u16* W2; const u16* bias = nullptr;
    if (MODE == 0)      { W1 = g_wb + OFF_QKVI; W2 = g_wb + OFF_QKVS; }
    else if (MODE == 1) { W1 = W2 = g_wb + OFF_PROJW; bias = g_wb + OFF_PROJB; }
    else if (MODE == 3) { W1 = W2 = g_wb + OFF_FC1W;  bias = g_wb + OFF_FC1B; }
    else                { W1 = W2 = g_wb + OFF_FC2W;  bias = g_wb + OFF_FC2B; }

    // XCD-chunked tile swizzle (consecutive logical tiles -> same XCD L2)
    const int gx = gridDim.x;
    const int nwg = gx * (int)gridDim.y;
    const int hw = blockIdx.y * gx + blockIdx.x;
    const int qq = nwg >> 3, rr = nwg & 7;
    const int xc = hw & 7, pp = hw >> 3;
    const int nid = (xc < rr ? xc * (qq + 1) : rr * (qq + 1) + (xc - rr) * qq) + pp;
    const int bx = nid % gx, by = nid / gx;

    const bool isGate = (MODE == 0) && (bx >= 6);
    const bool swp = (MODE == 0) ? (bx < 2 || isGate) : true;

    const int tid = threadIdx.x;
    const int lane = tid & 63;
    const int wv = tid >> 6;
    const int wm = wv >> 1, wn = wv & 1;
    const int quad = lane >> 4, lr = lane & 15;

    f32x4 acc[4][4];
    #pragma unroll
    for (int i = 0; i < 4; ++i)
        #pragma unroll
        for (int j = 0; j < 4; ++j) { f32x4 z = {0.f,0.f,0.f,0.f}; acc[i][j] = z; }

    const size_t arow0 = (size_t)by * BM;
    const int nbase_blk = isGate ? (bx - 6) * BN : bx * BN;    // W-row / out-col base
    const int ldw_eff = isGate ? 2 * CC : ldw;

    // staging: lane l fetches row (l&31), k-granule (l>>5)*8 [+16 on 2nd call]
    const int srow = lane & 31;
    const int sg   = (lane >> 5) << 3;     // 0 or 8 elements
    const size_t aoff = (arow0 + wv * 32 + srow) * (size_t)lda + sg;
    const size_t woff = ((size_t)nbase_blk + wv * 32 + srow) * (size_t)ldw_eff + sg;

    auto stage = [&](int buf, int k0) {
        const u16* As; const u16* Ws; int ka, kw;
        if (MODE == 0) {
            if (k0 < Ksplit) { As = isGate ? g_inb   : A1in; ka = k0; }
            else             { As = isGate ? g_prevb : A2in; ka = k0 - Ksplit; }
            if (isGate) { Ws = g_wb + OFF_GATEW; kw = k0; }
            else        { Ws = (k0 < Ksplit) ? W1 : W2;
                          kw = (k0 < Ksplit) ? k0 : k0 - Ksplit; }
        } else {
            As = A1in; Ws = W1; ka = k0; kw = k0;
        }
        const u16* ga = As + aoff + ka;
        u16* la = ash[buf] + (wv << 10);
        gl_lds16(ga, la);
        gl_lds16(ga + 16, la + 512);
        const u16* gw = Ws + woff + kw;
        u16* lb = bsh[buf] + (wv << 10);
        gl_lds16(gw, lb);
        gl_lds16(gw + 16, lb + 512);
    };

    auto compute = [&](int buf) {
        short8 af[4], bf[4];
        #pragma unroll
        for (int i = 0; i < 4; ++i) {
            const int ra = wm * 64 + i * 16 + lr;
            af[i] = *(const short8*)(ash[buf] + ((ra >> 5) << 10) + (quad << 8) + ((ra & 31) << 3));
        }
        #pragma unroll
        for (int j = 0; j < 4; ++j) {
            const int rb = wn * 64 + j * 16 + lr;
            bf[j] = *(const short8*)(bsh[buf] + ((rb >> 5) << 10) + (quad << 8) + ((rb & 31) << 3));
        }
        if (swp) {
            #pragma unroll
            for (int i = 0; i < 4; ++i)
                #pragma unroll
                for (int j = 0; j < 4; ++j)
                    acc[i][j] = __builtin_amdgcn_mfma_f32_16x16x32_bf16(bf[j], af[i], acc[i][j], 0, 0, 0);
        } else {
            #pragma unroll
            for (int i = 0; i < 4; ++i)
                #pragma unroll
                for (int j = 0; j < 4; ++j)
                    acc[i][j] = __builtin_amdgcn_mfma_f32_16x16x32_bf16(af[i], bf[j], acc[i][j], 0, 0, 0);
        }
    };

    const int NT = K / BK;        // >= 8 for all modes
    stage(0, 0);
    stage(1, BK);
    for (int t = 0; t < NT; ++t) {
        if (t + 2 < NT) {
            stage((t + 2) % 3, (t + 2) * BK);
            asm volatile("s_waitcnt vmcnt(8)" ::: "memory");   // my tile-t loads done
        } else if (t + 1 < NT) {
            asm volatile("s_waitcnt vmcnt(4)" ::: "memory");
        } else {
            asm volatile("s_waitcnt vmcnt(0)" ::: "memory");
        }
        __builtin_amdgcn_s_barrier();      // tile t complete for ALL waves
        asm volatile("" ::: "memory");
        compute(t % 3);
        asm volatile("" ::: "memory");
        __builtin_amdgcn_s_barrier();      // all waves done reading tile t
    }

    const int mbase = by * BM + wm * 64;
    const int nbase = nbase_blk + wn * 64;
    constexpr int LDOUT = (MODE == 3) ? HID : CC;

    #pragma unroll
    for (int i = 0; i < 4; ++i) {
        #pragma unroll
        for (int j = 0; j < 4; ++j) {
            if (MODE == 0) {
                if (isGate) {
                    // gate: u = sigmoid(acc + gateb) -> g_ugate (bf16)
                    const int m = mbase + i * 16 + lr;
                    const int c0 = nbase + j * 16 + quad * 4;   // 0..255
                    u16x4 b4 = *(const u16x4*)(g_wb + OFF_GATEB + c0);
                    u16x4 p;
                    #pragma unroll
                    for (int r = 0; r < 4; ++r) {
                        float u = 1.f / (1.f + __expf(-(acc[i][j][r] + b2f(b4[r]))));
                        p[r] = f2b(u);
                    }
                    *(u16x4*)(g_ugate + (size_t)m * CC + c0) = p;
                } else if (swp) {
                    // q third: row=token, cols = 4 consecutive d
                    const int m = mbase + i * 16 + lr;
                    const int b = m >> 12, n = m & (NN - 1);
                    const int c0 = nbase + j * 16 + quad * 4;  // < 256
                    const int h = c0 >> 5, d0 = c0 & 31;
                    u16x4 p;
                    #pragma unroll
                    for (int r = 0; r < 4; ++r) {
                        float v = acc[i][j][r];
                        p[r] = f2b((v > 0.f) ? (v + 1.f) : __expf(v));
                    }
                    *(u16x4*)(o0 + (((size_t)b * HH + h) * NN + n) * DD + d0) = p;
                } else {
                    // k/v thirds: unswapped; r traverses tokens -> [B,H,D,N] pack
                    const int c = nbase + j * 16 + lr;
                    const int which = c >> 8, rem = c & 255, h = rem >> 5, d = rem & 31;
                    const int m0 = mbase + i * 16 + quad * 4;
                    const int b = m0 >> 12, n0i = m0 & (NN - 1);
                    u16x4 p;
                    #pragma unroll
                    for (int r = 0; r < 4; ++r) {
                        float v = acc[i][j][r];
                        if (which == 1) v = (v > 0.f) ? (v + 1.f) : __expf(v);
                        p[r] = f2b(v);
                    }
                    u16* dst = o0 + (size_t)which * TOKEL;
                    *(u16x4*)(dst + (((size_t)b * HH + h) * DD + d) * NN + n0i) = p;
                }
            } else {
                // swapped: row m = mbase+i*16+lr, cols c0..c0+3
                const int m = mbase + i * 16 + lr;
                const int c0 = nbase + j * 16 + quad * 4;
                const size_t idx0 = (size_t)m * LDOUT + c0;
                float bias4[4];
                {
                    u16x4 t = *(const u16x4*)(bias + c0);
                    #pragma unroll
                    for (int r = 0; r < 4; ++r) bias4[r] = b2f(t[r]);
                }
                if (MODE == 1) {
                    u16x4 xa4 = *(const u16x4*)(xa + idx0);          // input_pos
                    u16x4 ug4 = *(const u16x4*)(g_ugate + idx0);     // u (bf16)
                    u16x4 po, pr;
                    float vals[4];
                    #pragma unroll
                    for (int r = 0; r < 4; ++r) {
                        float val = acc[i][j][r] + bias4[r];
                        vals[r] = val;
                        po[r] = f2b(val);                      // attn_proj
                        pr[r] = f2b(b2f(xa4[r]) + val);        // outpre
                    }
                    *(u16x4*)(o0 + idx0) = po;
                    *(u16x4*)(o1 + idx0) = pr;
                    // new_state = prev*(1-u) + attn*u  (old K6, now fused)
                    if (f32) {
                        f32x4 pv = *(const f32x4*)((const float*)xr + idx0);
                        f32x4 o;
                        #pragma unroll
                        for (int r = 0; r < 4; ++r) {
                            float u = b2f(ug4[r]);
                            o[r] = pv[r] * (1.f - u) + vals[r] * u;
                        }
                        *(f32x4*)((float*)oraw + TOKEL + idx0) = o;
                    } else {
                        u16x4 pv = *(const u16x4*)((const u16*)xr + idx0);
                        u16x4 o;
                        #pragma unroll
                        for (int r = 0; r < 4; ++r) {
                            float u = b2f(ug4[r]);
                            o[r] = f2b(b2f(pv[r]) * (1.f - u) + vals[r] * u);
                        }
                        *(u16x4*)((u16*)oraw + TOKEL + idx0) = o;
                    }
                } else if (MODE == 3) {
                    u16x4 p;
                    #pragma unroll
                    for (int r = 0; r < 4; ++r)
                        p[r] = f2b(gelu_f(acc[i][j][r] + bias4[r]));
                    *(u16x4*)(o0 + idx0) = p;
                } else {
                    u16x4 xa4 = *(const u16x4*)(xa + idx0);
                    if (f32) {
                        f32x4 o;
                        #pragma unroll
                        for (int r = 0; r < 4; ++r)
                            o[r] = b2f(xa4[r]) + acc[i][j][r] + bias4[r];
                        *(f32x4*)((float*)oraw + idx0) = o;
                    } else {
                        u16x4 o;
                        #pragma unroll
                        for (int r = 0; r < 4; ++r)
                            o[r] = f2b(b2f(xa4[r]) + acc[i][j][r] + bias4[r]);
                        *(u16x4*)((u16*)oraw + idx0) = o;
                    }
                }
            }
        }
    }
}

// =====================================================================
extern "C" void kernel_launch(void* const* d_in, const int* in_sizes, int n_in,
                              void* d_out, int out_size, void* d_ws, size_t ws_size,
                              hipStream_t stream)
{
    const void* input_ = d_in[0];
    const void* prev   = d_in[1];
    const void* pos    = d_in[2];
    const void* n1w = d_in[3];  const void* n1b = d_in[4];
    const void* n2w = d_in[5];  const void* n2b = d_in[6];
    const void* n3w = d_in[7];  const void* n3b = d_in[8];
    const void* qkvi = d_in[9]; const void* qkvs = d_in[10];
    const void* projw = d_in[11]; const void* projb = d_in[12];
    const void* gatew = d_in[13]; const void* gateb = d_in[14];
    const void* fc1w = d_in[15]; const void* fc1b = d_in[16];
    const void* fc2w = d_in[17]; const void* fc2b = d_in[18];

    char* ws = (char*)d_ws;
    u16* input_pos = (u16*)(ws + WS_INPUT_POS);
    u16* phiq  = (u16*)(ws + WS_PHIQ);
    u16* phikt = (u16*)(ws + WS_PHIK);
    u16* vt    = (u16*)(ws + WS_V);
    u16* x_ln = (u16*)(ws + WS_XLN);
    u16* s_ln = (u16*)(ws + WS_SLN);
    u16* attn_tok = x_ln;                  // reuse [K4..K5]
    u16* attn_proj = phikt;                // reuse [K5..end]
    float* kvf = (float*)(ws + WS_SLN);    // reuse [K3..K4]
    u16* ln3o = s_ln;                      // reuse [K7..K8]
    u16* outpre = (u16*)(ws + WS_OUTPRE);
    u16* h1 = (u16*)(ws + WS_INPUT_POS);   // overlays 0..64MiB (dead by K8)
    int* flagp = (int*)(ws + WS_FLAG);

    // K0 dtype detect
    detect_kernel<<<1, 64, 0, stream>>>((const u16*)input_, flagp);
    // K0b convert weights/biases to bf16 table
    wconv_kernel<<<(WTOT + 255) / 256, 256, 0, stream>>>(
        qkvi, qkvs, projw, gatew, fc1w, fc2w, projb, gateb, fc1b, fc2b, flagp);
    // K1 prep (+ bf16 dumps of input_/prev)
    prep_kernel<<<MTOK, 256, 0, stream>>>(input_, prev, pos, n1w, n1b, n2w, n2b,
                                          input_pos, x_ln, s_ln, flagp);
    // K2 FUSED qkv+gate: bx 0..5 qkv (q/k/v packs), bx 6..7 gate u-map
    gemm_bt<0><<<dim3(8, MTOK / BM), 256, 0, stream>>>(
        x_ln, s_ln, CC, CC, 2 * CC, CC, 0,
        phiq, nullptr, nullptr, nullptr, nullptr, flagp);
    // K3 kv einsum (MFMA split-K + atomics)
    hipMemsetAsync((void*)kvf, 0, BB * HH * DD * DD * sizeof(float), stream);
    kv_mfma<<<dim3(BB * HH, 16), 64, 0, stream>>>(phikt, vt, kvf);
    // K4 attn tokens (MFMA)
    attn_mfma<<<dim3(BB * HH, NN / 512), 256, 0, stream>>>(phiq, kvf, attn_tok);
    // K5 proj + outpre + new_state (fused old K6 epilogue)
    gemm_bt<1><<<dim3(CC / BN, MTOK / BM), 256, 0, stream>>>(
        attn_tok, attn_tok, CC, CC, CC, CC, 0,
        attn_proj, outpre, input_pos, prev, d_out, flagp);
    // K7 LN3
    ln3_kernel<<<MTOK, 256, 0, stream>>>(outpre, n3w, n3b, ln3o, flagp);
    // K8 fc1 + gelu
    gemm_bt<3><<<dim3(HID / BN, MTOK / BM), 256, 0, stream>>>(
        ln3o, ln3o, CC, CC, CC, CC, 0,
        h1, nullptr, nullptr, nullptr, nullptr, flagp);
    // K9 fc2 + final residual -> d_out[output]
    gemm_bt<4><<<dim3(CC / BN, MTOK / BM), 256, 0, stream>>>(
        h1, h1, HID, HID, HID, HID, 0,
        nullptr, nullptr, outpre, nullptr, d_out, flagp);
}

// Round 9
// 428.352 us; speedup vs baseline: 1.2495x; 1.2078x over previous
//
#include <hip/hip_runtime.h>
#include <cmath>

typedef unsigned short u16;
typedef __attribute__((ext_vector_type(8))) short short8;
typedef __attribute__((ext_vector_type(4))) float f32x4;
typedef __attribute__((ext_vector_type(4))) u16 u16x4;

// ---------- bf16 helpers ----------
__device__ __forceinline__ float b2f(u16 u) {
    unsigned x = ((unsigned)u) << 16;
    return __builtin_bit_cast(float, x);
}
__device__ __forceinline__ u16 f2b(float f) {
    unsigned x = __builtin_bit_cast(unsigned, f);
    unsigned r = (x + 0x7fffu + ((x >> 16) & 1u)) >> 16;   // RNE
    return (u16)r;
}
// dtype-adaptive load (f32 flag is wave-uniform)
__device__ __forceinline__ float loadx(const void* p, size_t i, int f32) {
    return f32 ? ((const float*)p)[i] : b2f(((const u16*)p)[i]);
}
// async global->LDS, 16B per lane; LDS dest = wave-uniform base + lane*16
__device__ __forceinline__ void gl_lds16(const void* g, void* l) {
    __builtin_amdgcn_global_load_lds(
        (const __attribute__((address_space(1))) void*)g,
        (__attribute__((address_space(3))) void*)l, 16, 0, 0);
}
// fast gelu (tanh form)
__device__ __forceinline__ float gelu_f(float x) {
    float y = 0.7978845608028654f * (x + 0.044715f * x * x * x);
    float e = __expf(2.f * y);
    float t = 1.f - 2.f / (e + 1.f);    // tanh(y)
    return 0.5f * x * (1.f + t);
}

// ---------- problem constants ----------
#define BB 8
#define NN 4096
#define CC 256
#define HH 8
#define DD 32
#define HID 1024
#define MTOK (BB*NN)             // 32768 tokens
#define TOKEL ((size_t)MTOK*CC)  // 8388608 elements per [M,C] tensor
#define TOKELC 8388608

// ws offsets (bytes) — unchanged (112 MiB + 4)
#define WS_INPUT_POS 0u
#define WS_PHIQ   16777216u
#define WS_PHIK   33554432u
#define WS_V      50331648u
#define WS_XLN    67108864u
#define WS_SLN    83886080u
#define WS_OUTPRE 100663296u
#define WS_FLAG   117440512u

// ---------- bf16 weight table (device globals; zero-init BSS) ----------
#define OFF_QKVI  0u
#define OFF_QKVS  196608u
#define OFF_PROJW 393216u
#define OFF_GATEW 458752u
#define OFF_FC1W  589824u
#define OFF_FC2W  851968u
#define OFF_PROJB 1114112u
#define OFF_GATEB 1114368u
#define OFF_FC1B  1114624u
#define OFF_FC2B  1115648u
#define WTOT      1115904u

__device__ __attribute__((aligned(16))) u16 g_wb[WTOT];
__device__ __attribute__((aligned(16))) u16 g_inb[TOKELC];   // bf16 copy of input_
__device__ __attribute__((aligned(16))) u16 g_prevb[TOKELC]; // bf16 copy of prev_state
__device__ __attribute__((aligned(16))) u16 g_ugate[TOKELC]; // u = sigmoid(gate) bf16

// =====================================================================
// K0: detect input dtype
// =====================================================================
__global__ __launch_bounds__(64) void detect_kernel(const u16* __restrict__ in0,
                                                    int* __restrict__ flag)
{
    int t = threadIdx.x;
    u16 w = in0[2 * t];
    int e = (w >> 7) & 0xFF;
    int bad = (e < 64 || e > 192) ? 1 : 0;
    unsigned long long m = __ballot(bad);
    if (t == 0) *flag = (__popcll(m) > 8) ? 1 : 0;
}

// =====================================================================
// K0b: convert all GEMM weights + biases to one bf16 table (once)
// =====================================================================
__global__ __launch_bounds__(256) void wconv_kernel(
    const void* qkvi, const void* qkvs, const void* projw, const void* gatew,
    const void* fc1w, const void* fc2w, const void* projb, const void* gateb,
    const void* fc1b, const void* fc2b, const int* __restrict__ flagp)
{
    const int f32 = *flagp;
    unsigned i = blockIdx.x * 256 + threadIdx.x;
    if (i >= WTOT) return;
    const void* src; unsigned off;
    if      (i < OFF_QKVS)  { src = qkvi;  off = OFF_QKVI; }
    else if (i < OFF_PROJW) { src = qkvs;  off = OFF_QKVS; }
    else if (i < OFF_GATEW) { src = projw; off = OFF_PROJW; }
    else if (i < OFF_FC1W)  { src = gatew; off = OFF_GATEW; }
    else if (i < OFF_FC2W)  { src = fc1w;  off = OFF_FC1W; }
    else if (i < OFF_PROJB) { src = fc2w;  off = OFF_FC2W; }
    else if (i < OFF_GATEB) { src = projb; off = OFF_PROJB; }
    else if (i < OFF_FC1B)  { src = gateb; off = OFF_GATEB; }
    else if (i < OFF_FC2B)  { src = fc1b;  off = OFF_FC1B; }
    else                    { src = fc2b;  off = OFF_FC2B; }
    g_wb[i] = f2b(loadx(src, i - off, f32));
}

// =====================================================================
// K1: wave-per-row prep (4 rows/block, no barriers, vector loads):
// input_pos = input_+pos ; x_ln = LN1(input_pos) ; s_ln = LN2(prev)
// + bf16 dumps g_inb/g_prevb for the gate GEMM A-operand
// =====================================================================
__global__ __launch_bounds__(256) void prep_kernel(
    const void* __restrict__ inp, const void* __restrict__ prev,
    const void* __restrict__ pos,
    const void* __restrict__ w1, const void* __restrict__ b1,
    const void* __restrict__ w2, const void* __restrict__ b2,
    u16* __restrict__ input_pos, u16* __restrict__ x_ln, u16* __restrict__ s_ln,
    const int* __restrict__ flagp)
{
    const int f32 = *flagp;
    const int m = blockIdx.x * 4 + (threadIdx.x >> 6);
    const int lane = threadIdx.x & 63;
    const int e0 = lane * 4;
    const int n = m & (NN - 1);
    const size_t idx = (size_t)m * CC + e0;

    float inr[4], ip[4];
    if (f32) {
        f32x4 a = *(const f32x4*)((const float*)inp + idx);
        f32x4 p = *(const f32x4*)((const float*)pos + (size_t)n * CC + e0);
        #pragma unroll
        for (int r = 0; r < 4; ++r) { inr[r] = a[r]; ip[r] = a[r] + p[r]; }
    } else {
        u16x4 a = *(const u16x4*)((const u16*)inp + idx);
        u16x4 p = *(const u16x4*)((const u16*)pos + (size_t)n * CC + e0);
        #pragma unroll
        for (int r = 0; r < 4; ++r) { inr[r] = b2f(a[r]); ip[r] = inr[r] + b2f(p[r]); }
    }
    {
        u16x4 gi;
        #pragma unroll
        for (int r = 0; r < 4; ++r) gi[r] = f2b(inr[r]);
        *(u16x4*)(g_inb + idx) = gi;
    }
    float s = 0.f, s2 = 0.f;
    #pragma unroll
    for (int r = 0; r < 4; ++r) { s += ip[r]; s2 += ip[r] * ip[r]; }
    #pragma unroll
    for (int o = 1; o < 64; o <<= 1) { s += __shfl_xor(s, o, 64); s2 += __shfl_xor(s2, o, 64); }
    float mu = s * (1.f / 256.f);
    float rs = rsqrtf(s2 * (1.f / 256.f) - mu * mu + 1e-5f);
    float wv[4], bv[4];
    if (f32) {
        f32x4 w4 = *(const f32x4*)((const float*)w1 + e0);
        f32x4 b4 = *(const f32x4*)((const float*)b1 + e0);
        #pragma unroll
        for (int r = 0; r < 4; ++r) { wv[r] = w4[r]; bv[r] = b4[r]; }
    } else {
        u16x4 w4 = *(const u16x4*)((const u16*)w1 + e0);
        u16x4 b4 = *(const u16x4*)((const u16*)b1 + e0);
        #pragma unroll
        for (int r = 0; r < 4; ++r) { wv[r] = b2f(w4[r]); bv[r] = b2f(b4[r]); }
    }
    {
        u16x4 ipo, xo;
        #pragma unroll
        for (int r = 0; r < 4; ++r) {
            ipo[r] = f2b(ip[r]);
            xo[r]  = f2b((ip[r] - mu) * rs * wv[r] + bv[r]);
        }
        *(u16x4*)(input_pos + idx) = ipo;
        *(u16x4*)(x_ln + idx) = xo;
    }

    // prev pass
    float pv[4];
    if (f32) {
        f32x4 a = *(const f32x4*)((const float*)prev + idx);
        #pragma unroll
        for (int r = 0; r < 4; ++r) pv[r] = a[r];
    } else {
        u16x4 a = *(const u16x4*)((const u16*)prev + idx);
        #pragma unroll
        for (int r = 0; r < 4; ++r) pv[r] = b2f(a[r]);
    }
    {
        u16x4 gp;
        #pragma unroll
        for (int r = 0; r < 4; ++r) gp[r] = f2b(pv[r]);
        *(u16x4*)(g_prevb + idx) = gp;
    }
    s = 0.f; s2 = 0.f;
    #pragma unroll
    for (int r = 0; r < 4; ++r) { s += pv[r]; s2 += pv[r] * pv[r]; }
    #pragma unroll
    for (int o = 1; o < 64; o <<= 1) { s += __shfl_xor(s, o, 64); s2 += __shfl_xor(s2, o, 64); }
    mu = s * (1.f / 256.f);
    rs = rsqrtf(s2 * (1.f / 256.f) - mu * mu + 1e-5f);
    if (f32) {
        f32x4 w4 = *(const f32x4*)((const float*)w2 + e0);
        f32x4 b4 = *(const f32x4*)((const float*)b2 + e0);
        #pragma unroll
        for (int r = 0; r < 4; ++r) { wv[r] = w4[r]; bv[r] = b4[r]; }
    } else {
        u16x4 w4 = *(const u16x4*)((const u16*)w2 + e0);
        u16x4 b4 = *(const u16x4*)((const u16*)b2 + e0);
        #pragma unroll
        for (int r = 0; r < 4; ++r) { wv[r] = b2f(w4[r]); bv[r] = b2f(b4[r]); }
    }
    {
        u16x4 so;
        #pragma unroll
        for (int r = 0; r < 4; ++r) so[r] = f2b((pv[r] - mu) * rs * wv[r] + bv[r]);
        *(u16x4*)(s_ln + idx) = so;
    }
}

// =====================================================================
// K7': ln3_out = LN3(outpre) AND new_state = prev*(1-u) + attn_proj*u
// wave-per-row, 4 rows/block, no barriers. Blend numerics = R6's K6
// (bf16 attn_proj; bf16 u verified in R8).
// =====================================================================
__global__ __launch_bounds__(256) void ln3_blend_kernel(
    const u16* __restrict__ op, const void* __restrict__ w,
    const void* __restrict__ b, u16* __restrict__ out,
    const u16* __restrict__ ap, const void* __restrict__ prevraw,
    void* __restrict__ dout, const int* __restrict__ flagp)
{
    const int f32 = *flagp;
    const int m = blockIdx.x * 4 + (threadIdx.x >> 6);
    const int lane = threadIdx.x & 63;
    const int e0 = lane * 4;
    const size_t idx = (size_t)m * CC + e0;

    u16x4 x4 = *(const u16x4*)(op + idx);
    float x[4];
    #pragma unroll
    for (int r = 0; r < 4; ++r) x[r] = b2f(x4[r]);
    float s = 0.f, s2 = 0.f;
    #pragma unroll
    for (int r = 0; r < 4; ++r) { s += x[r]; s2 += x[r] * x[r]; }
    #pragma unroll
    for (int o = 1; o < 64; o <<= 1) { s += __shfl_xor(s, o, 64); s2 += __shfl_xor(s2, o, 64); }
    float mu = s * (1.f / 256.f);
    float rs = rsqrtf(s2 * (1.f / 256.f) - mu * mu + 1e-5f);
    float wv[4], bv[4];
    if (f32) {
        f32x4 w4 = *(const f32x4*)((const float*)w + e0);
        f32x4 b4 = *(const f32x4*)((const float*)b + e0);
        #pragma unroll
        for (int r = 0; r < 4; ++r) { wv[r] = w4[r]; bv[r] = b4[r]; }
    } else {
        u16x4 w4 = *(const u16x4*)((const u16*)w + e0);
        u16x4 b4 = *(const u16x4*)((const u16*)b + e0);
        #pragma unroll
        for (int r = 0; r < 4; ++r) { wv[r] = b2f(w4[r]); bv[r] = b2f(b4[r]); }
    }
    {
        u16x4 o4;
        #pragma unroll
        for (int r = 0; r < 4; ++r) o4[r] = f2b((x[r] - mu) * rs * wv[r] + bv[r]);
        *(u16x4*)(out + idx) = o4;
    }

    // new_state blend
    u16x4 a4 = *(const u16x4*)(ap + idx);
    u16x4 u4 = *(const u16x4*)(g_ugate + idx);
    if (f32) {
        f32x4 pv = *(const f32x4*)((const float*)prevraw + idx);
        f32x4 o;
        #pragma unroll
        for (int r = 0; r < 4; ++r) {
            float u = b2f(u4[r]);
            o[r] = pv[r] * (1.f - u) + b2f(a4[r]) * u;
        }
        *(f32x4*)((float*)dout + TOKEL + idx) = o;
    } else {
        u16x4 pv = *(const u16x4*)((const u16*)prevraw + idx);
        u16x4 o;
        #pragma unroll
        for (int r = 0; r < 4; ++r) {
            float u = b2f(u4[r]);
            o[r] = f2b(b2f(pv[r]) * (1.f - u) + b2f(a4[r]) * u);
        }
        *(u16x4*)((u16*)dout + TOKEL + idx) = o;
    }
}

// =====================================================================
// K3: kv[bh][d][e] = sum_n phik_t[bh][d][n] * v_t[bh][e][n]
// =====================================================================
__global__ __launch_bounds__(64) void kv_mfma(
    const u16* __restrict__ phik_t, const u16* __restrict__ v_t,
    float* __restrict__ kvout)
{
    const int bh = blockIdx.x;
    const int k0 = blockIdx.y * 256;
    const int lane = threadIdx.x;
    const int quad = lane >> 4, lr = lane & 15;

    const u16* A = phik_t + (size_t)bh * DD * NN;
    const u16* W = v_t    + (size_t)bh * DD * NN;

    f32x4 acc[2][2];
    #pragma unroll
    for (int i = 0; i < 2; ++i)
        #pragma unroll
        for (int j = 0; j < 2; ++j) { f32x4 z = {0.f,0.f,0.f,0.f}; acc[i][j] = z; }

    for (int kk = k0; kk < k0 + 256; kk += 32) {
        short8 a0 = *(const short8*)(A + (size_t)lr * NN + kk + quad * 8);
        short8 a1 = *(const short8*)(A + (size_t)(16 + lr) * NN + kk + quad * 8);
        short8 w0 = *(const short8*)(W + (size_t)lr * NN + kk + quad * 8);
        short8 w1 = *(const short8*)(W + (size_t)(16 + lr) * NN + kk + quad * 8);
        acc[0][0] = __builtin_amdgcn_mfma_f32_16x16x32_bf16(a0, w0, acc[0][0], 0, 0, 0);
        acc[0][1] = __builtin_amdgcn_mfma_f32_16x16x32_bf16(a0, w1, acc[0][1], 0, 0, 0);
        acc[1][0] = __builtin_amdgcn_mfma_f32_16x16x32_bf16(a1, w0, acc[1][0], 0, 0, 0);
        acc[1][1] = __builtin_amdgcn_mfma_f32_16x16x32_bf16(a1, w1, acc[1][1], 0, 0, 0);
    }
    float* base = kvout + (size_t)bh * (DD * DD);
    #pragma unroll
    for (int i = 0; i < 2; ++i)
        #pragma unroll
        for (int j = 0; j < 2; ++j)
            #pragma unroll
            for (int r = 0; r < 4; ++r)
                atomicAdd(base + (i * 16 + quad * 4 + r) * DD + j * 16 + lr, acc[i][j][r]);
}

// =====================================================================
// K4: attn_tok[b,n, h*32+e] = sum_d phiq[b,h,n,d] * kv[b,h][d][e]  (MFMA)
// =====================================================================
__global__ __launch_bounds__(256) void attn_mfma(
    const u16* __restrict__ phiq, const float* __restrict__ kv,
    u16* __restrict__ attn_tok)
{
    const int bh = blockIdx.x;
    const int b = bh >> 3, h = bh & 7;
    const int wv = threadIdx.x >> 6, lane = threadIdx.x & 63;
    const int quad = lane >> 4, lr = lane & 15;

    const float* kvb = kv + (size_t)bh * (DD * DD);
    short8 bf0, bf1;
    #pragma unroll
    for (int j = 0; j < 8; ++j) {
        int d = quad * 8 + j;
        bf0[j] = (short)f2b(kvb[d * DD + lr]);
        bf1[j] = (short)f2b(kvb[d * DD + 16 + lr]);
    }

    const u16* qb = phiq + (size_t)bh * NN * DD;
    const int n0 = blockIdx.y * 512 + wv * 128;
    #pragma unroll
    for (int t = 0; t < 8; ++t) {
        const int nt = n0 + t * 16;
        short8 af = *(const short8*)(qb + (size_t)(nt + lr) * DD + quad * 8);
        f32x4 c0 = {0.f,0.f,0.f,0.f}, c1 = {0.f,0.f,0.f,0.f};
        c0 = __builtin_amdgcn_mfma_f32_16x16x32_bf16(af, bf0, c0, 0, 0, 0);
        c1 = __builtin_amdgcn_mfma_f32_16x16x32_bf16(af, bf1, c1, 0, 0, 0);
        size_t base = ((size_t)b * NN + nt + quad * 4) * CC + h * DD;
        #pragma unroll
        for (int r = 0; r < 4; ++r) {
            attn_tok[base + (size_t)r * CC + lr]      = f2b(c0[r]);
            attn_tok[base + (size_t)r * CC + 16 + lr] = f2b(c1[r]);
        }
    }
}

// =====================================================================
// MFMA GEMM (R6-verified counted-vmcnt triple-buffer loop).
// MODE 0: qkv (R6 exact: bx<2 q-scatter, bx 2..5 k/v pack).
// MODE 1: FUSED proj+gate (both small, mutually independent):
//   bx 0..1 -> proj (attn_proj + outpre epilogue, K=256);
//   bx 2..3 -> gate (A=[g_inb|g_prevb], W=gatew 256x512, K=512,
//               epilogue u=sigmoid(acc+gateb) -> g_ugate, R8-verified).
// MODE 3: fc1+gelu.  MODE 4: fc2+residual.
// =====================================================================
#define BM 128
#define BN 128
#define BK 32

template <int MODE>
__global__ __launch_bounds__(256) void gemm_bt(
    const u16* __restrict__ A1in, const u16* __restrict__ A2in,
    int lda, int ldw, int K, int Ksplit, int wcol2,
    u16* __restrict__ o0, u16* __restrict__ o1,
    const u16* __restrict__ xa, const void* __restrict__ xr,
    void* __restrict__ oraw, const int* __restrict__ flagp)
{
    __shared__ __attribute__((aligned(16))) u16 ash[3][BM * BK];
    __shared__ __attribute__((aligned(16))) u16 bsh[3][BN * BK];

    const int f32 = (MODE == 4) ? *flagp : 0;

    const u16* W1; const u16* W2; const u16* bias = nullptr;
    if (MODE == 0)      { W1 = g_wb + OFF_QKVI; W2 = g_wb + OFF_QKVS; }
    else if (MODE == 1) { W1 = W2 = g_wb + OFF_PROJW; bias = g_wb + OFF_PROJB; }
    else if (MODE == 3) { W1 = W2 = g_wb + OFF_FC1W;  bias = g_wb + OFF_FC1B; }
    else                { W1 = W2 = g_wb + OFF_FC2W;  bias = g_wb + OFF_FC2B; }

    // XCD-chunked tile swizzle (consecutive logical tiles -> same XCD L2)
    const int gx = gridDim.x;
    const int nwg = gx * (int)gridDim.y;
    const int hw = blockIdx.y * gx + blockIdx.x;
    const int qq = nwg >> 3, rr = nwg & 7;
    const int xc = hw & 7, pp = hw >> 3;
    const int nid = (xc < rr ? xc * (qq + 1) : rr * (qq + 1) + (xc - rr) * qq) + pp;
    const int bx = nid % gx, by = nid / gx;

    const bool isGate = (MODE == 1) && (bx >= 2);
    const bool swp = (MODE == 0) ? (bx < 2) : true;

    const int tid = threadIdx.x;
    const int lane = tid & 63;
    const int wv = tid >> 6;
    const int wm = wv >> 1, wn = wv & 1;
    const int quad = lane >> 4, lr = lane & 15;

    f32x4 acc[4][4];
    #pragma unroll
    for (int i = 0; i < 4; ++i)
        #pragma unroll
        for (int j = 0; j < 4; ++j) { f32x4 z = {0.f,0.f,0.f,0.f}; acc[i][j] = z; }

    const size_t arow0 = (size_t)by * BM;
    const int nbase_blk = isGate ? (bx - 2) * BN : bx * BN;
    const int ldw_eff = isGate ? 2 * CC : ldw;
    const int Keff = isGate ? 2 * CC : K;

    // staging: lane l fetches row (l&31), k-granule (l>>5)*8 [+16 on 2nd call]
    const int srow = lane & 31;
    const int sg   = (lane >> 5) << 3;     // 0 or 8 elements
    const size_t aoff = (arow0 + wv * 32 + srow) * (size_t)lda + sg;
    const size_t woff = ((size_t)nbase_blk + wv * 32 + srow) * (size_t)ldw_eff + sg;

    auto stage = [&](int buf, int k0) {
        const u16* As; const u16* Ws; int ka, kw;
        if (isGate) {
            As = (k0 < CC) ? g_inb : g_prevb; ka = k0 & (CC - 1);
            Ws = g_wb + OFF_GATEW; kw = k0;
        } else if (MODE == 0) {
            if (k0 < Ksplit) { As = A1in; Ws = W1; ka = k0;          kw = k0; }
            else             { As = A2in; Ws = W2; ka = k0 - Ksplit; kw = k0 - Ksplit; }
        } else {
            As = A1in; Ws = W1; ka = k0; kw = k0;
        }
        const u16* ga = As + aoff + ka;
        u16* la = ash[buf] + (wv << 10);
        gl_lds16(ga, la);
        gl_lds16(ga + 16, la + 512);
        const u16* gw = Ws + woff + kw;
        u16* lb = bsh[buf] + (wv << 10);
        gl_lds16(gw, lb);
        gl_lds16(gw + 16, lb + 512);
    };

    auto compute = [&](int buf) {
        short8 af[4], bf[4];
        #pragma unroll
        for (int i = 0; i < 4; ++i) {
            const int ra = wm * 64 + i * 16 + lr;
            af[i] = *(const short8*)(ash[buf] + ((ra >> 5) << 10) + (quad << 8) + ((ra & 31) << 3));
        }
        #pragma unroll
        for (int j = 0; j < 4; ++j) {
            const int rb = wn * 64 + j * 16 + lr;
            bf[j] = *(const short8*)(bsh[buf] + ((rb >> 5) << 10) + (quad << 8) + ((rb & 31) << 3));
        }
        if (swp) {
            #pragma unroll
            for (int i = 0; i < 4; ++i)
                #pragma unroll
                for (int j = 0; j < 4; ++j)
                    acc[i][j] = __builtin_amdgcn_mfma_f32_16x16x32_bf16(bf[j], af[i], acc[i][j], 0, 0, 0);
        } else {
            #pragma unroll
            for (int i = 0; i < 4; ++i)
                #pragma unroll
                for (int j = 0; j < 4; ++j)
                    acc[i][j] = __builtin_amdgcn_mfma_f32_16x16x32_bf16(af[i], bf[j], acc[i][j], 0, 0, 0);
        }
    };

    const int NT = Keff / BK;     // >= 8 for all modes
    stage(0, 0);
    stage(1, BK);
    for (int t = 0; t < NT; ++t) {
        if (t + 2 < NT) {
            stage((t + 2) % 3, (t + 2) * BK);
            asm volatile("s_waitcnt vmcnt(8)" ::: "memory");   // my tile-t loads done
        } else if (t + 1 < NT) {
            asm volatile("s_waitcnt vmcnt(4)" ::: "memory");
        } else {
            asm volatile("s_waitcnt vmcnt(0)" ::: "memory");
        }
        __builtin_amdgcn_s_barrier();      // tile t complete for ALL waves
        asm volatile("" ::: "memory");
        compute(t % 3);
        asm volatile("" ::: "memory");
        __builtin_amdgcn_s_barrier();      // all waves done reading tile t
    }

    const int mbase = by * BM + wm * 64;
    const int nbase = nbase_blk + wn * 64;
    constexpr int LDOUT = (MODE == 3) ? HID : CC;

    #pragma unroll
    for (int i = 0; i < 4; ++i) {
        #pragma unroll
        for (int j = 0; j < 4; ++j) {
            if (MODE == 0) {
                if (swp) {
                    // q third: row=token, cols = 4 consecutive d
                    const int m = mbase + i * 16 + lr;
                    const int b = m >> 12, n = m & (NN - 1);
                    const int c0 = nbase + j * 16 + quad * 4;  // < 256
                    const int h = c0 >> 5, d0 = c0 & 31;
                    u16x4 p;
                    #pragma unroll
                    for (int r = 0; r < 4; ++r) {
                        float v = acc[i][j][r];
                        p[r] = f2b((v > 0.f) ? (v + 1.f) : __expf(v));
                    }
                    *(u16x4*)(o0 + (((size_t)b * HH + h) * NN + n) * DD + d0) = p;
                } else {
                    // k/v thirds: unswapped; r traverses tokens -> [B,H,D,N] pack
                    const int c = nbase + j * 16 + lr;
                    const int which = c >> 8, rem = c & 255, h = rem >> 5, d = rem & 31;
                    const int m0 = mbase + i * 16 + quad * 4;
                    const int b = m0 >> 12, n0i = m0 & (NN - 1);
                    u16x4 p;
                    #pragma unroll
                    for (int r = 0; r < 4; ++r) {
                        float v = acc[i][j][r];
                        if (which == 1) v = (v > 0.f) ? (v + 1.f) : __expf(v);
                        p[r] = f2b(v);
                    }
                    u16* dst = o0 + (size_t)which * TOKEL;
                    *(u16x4*)(dst + (((size_t)b * HH + h) * DD + d) * NN + n0i) = p;
                }
            } else if (MODE == 1) {
                const int m = mbase + i * 16 + lr;
                const int c0 = nbase + j * 16 + quad * 4;
                const size_t idx0 = (size_t)m * CC + c0;
                if (isGate) {
                    // u = sigmoid(acc + gateb) -> g_ugate (bf16) [R8-verified]
                    u16x4 b4 = *(const u16x4*)(g_wb + OFF_GATEB + c0);
                    u16x4 p;
                    #pragma unroll
                    for (int r = 0; r < 4; ++r) {
                        float u = 1.f / (1.f + __expf(-(acc[i][j][r] + b2f(b4[r]))));
                        p[r] = f2b(u);
                    }
                    *(u16x4*)(g_ugate + idx0) = p;
                } else {
                    u16x4 b4 = *(const u16x4*)(bias + c0);
                    u16x4 xa4 = *(const u16x4*)(xa + idx0);      // input_pos
                    u16x4 po, pr;
                    #pragma unroll
                    for (int r = 0; r < 4; ++r) {
                        float val = acc[i][j][r] + b2f(b4[r]);
                        po[r] = f2b(val);                      // attn_proj
                        pr[r] = f2b(b2f(xa4[r]) + val);        // outpre
                    }
                    *(u16x4*)(o0 + idx0) = po;
                    *(u16x4*)(o1 + idx0) = pr;
                }
            } else {
                // swapped: row m = mbase+i*16+lr, cols c0..c0+3
                const int m = mbase + i * 16 + lr;
                const int c0 = nbase + j * 16 + quad * 4;
                const size_t idx0 = (size_t)m * LDOUT + c0;
                float bias4[4];
                {
                    u16x4 t = *(const u16x4*)(bias + c0);
                    #pragma unroll
                    for (int r = 0; r < 4; ++r) bias4[r] = b2f(t[r]);
                }
                if (MODE == 3) {
                    u16x4 p;
                    #pragma unroll
                    for (int r = 0; r < 4; ++r)
                        p[r] = f2b(gelu_f(acc[i][j][r] + bias4[r]));
                    *(u16x4*)(o0 + idx0) = p;
                } else {
                    u16x4 xa4 = *(const u16x4*)(xa + idx0);
                    if (f32) {
                        f32x4 o;
                        #pragma unroll
                        for (int r = 0; r < 4; ++r)
                            o[r] = b2f(xa4[r]) + acc[i][j][r] + bias4[r];
                        *(f32x4*)((float*)oraw + idx0) = o;
                    } else {
                        u16x4 o;
                        #pragma unroll
                        for (int r = 0; r < 4; ++r)
                            o[r] = f2b(b2f(xa4[r]) + acc[i][j][r] + bias4[r]);
                        *(u16x4*)((u16*)oraw + idx0) = o;
                    }
                }
            }
        }
    }
}

// =====================================================================
extern "C" void kernel_launch(void* const* d_in, const int* in_sizes, int n_in,
                              void* d_out, int out_size, void* d_ws, size_t ws_size,
                              hipStream_t stream)
{
    const void* input_ = d_in[0];
    const void* prev   = d_in[1];
    const void* pos    = d_in[2];
    const void* n1w = d_in[3];  const void* n1b = d_in[4];
    const void* n2w = d_in[5];  const void* n2b = d_in[6];
    const void* n3w = d_in[7];  const void* n3b = d_in[8];
    const void* qkvi = d_in[9]; const void* qkvs = d_in[10];
    const void* projw = d_in[11]; const void* projb = d_in[12];
    const void* gatew = d_in[13]; const void* gateb = d_in[14];
    const void* fc1w = d_in[15]; const void* fc1b = d_in[16];
    const void* fc2w = d_in[17]; const void* fc2b = d_in[18];

    char* ws = (char*)d_ws;
    u16* input_pos = (u16*)(ws + WS_INPUT_POS);
    u16* phiq  = (u16*)(ws + WS_PHIQ);
    u16* phikt = (u16*)(ws + WS_PHIK);
    u16* vt    = (u16*)(ws + WS_V);
    u16* x_ln = (u16*)(ws + WS_XLN);
    u16* s_ln = (u16*)(ws + WS_SLN);
    u16* attn_tok = x_ln;                  // reuse [K4..K5]
    u16* attn_proj = phikt;                // reuse [K5..K7'] (dead before K8's h1)
    float* kvf = (float*)(ws + WS_SLN);    // reuse [K3..K4]
    u16* ln3o = s_ln;                      // reuse [K7'..K8]
    u16* outpre = (u16*)(ws + WS_OUTPRE);
    u16* h1 = (u16*)(ws + WS_INPUT_POS);   // overlays 0..64MiB (dead by K8)
    int* flagp = (int*)(ws + WS_FLAG);

    // K0 dtype detect
    detect_kernel<<<1, 64, 0, stream>>>((const u16*)input_, flagp);
    // K0b convert weights/biases to bf16 table
    wconv_kernel<<<(WTOT + 255) / 256, 256, 0, stream>>>(
        qkvi, qkvs, projw, gatew, fc1w, fc2w, projb, gateb, fc1b, fc2b, flagp);
    // K1 prep (wave-per-row, vectorized, barrier-free)
    prep_kernel<<<MTOK / 4, 256, 0, stream>>>(input_, prev, pos, n1w, n1b, n2w, n2b,
                                              input_pos, x_ln, s_ln, flagp);
    // K2 qkv (R6 exact): q->[B,H,N,D], k/v->[B,H,D,N]
    gemm_bt<0><<<dim3(3 * CC / BN, MTOK / BM), 256, 0, stream>>>(
        x_ln, s_ln, CC, CC, 2 * CC, CC, 0,
        phiq, nullptr, nullptr, nullptr, nullptr, flagp);
    // K3 kv einsum (MFMA split-K + atomics)
    hipMemsetAsync((void*)kvf, 0, BB * HH * DD * DD * sizeof(float), stream);
    kv_mfma<<<dim3(BB * HH, 16), 64, 0, stream>>>(phikt, vt, kvf);
    // K4 attn tokens (MFMA)
    attn_mfma<<<dim3(BB * HH, NN / 512), 256, 0, stream>>>(phiq, kvf, attn_tok);
    // K5' FUSED proj+gate: bx 0..1 proj, bx 2..3 gate (u -> g_ugate)
    gemm_bt<1><<<dim3(4, MTOK / BM), 256, 0, stream>>>(
        attn_tok, attn_tok, CC, CC, CC, CC, 0,
        attn_proj, outpre, input_pos, nullptr, nullptr, flagp);
    // K7' LN3 + new_state blend
    ln3_blend_kernel<<<MTOK / 4, 256, 0, stream>>>(
        outpre, n3w, n3b, ln3o, attn_proj, prev, d_out, flagp);
    // K8 fc1 + gelu
    gemm_bt<3><<<dim3(HID / BN, MTOK / BM), 256, 0, stream>>>(
        ln3o, ln3o, CC, CC, CC, CC, 0,
        h1, nullptr, nullptr, nullptr, nullptr, flagp);
    // K9 fc2 + final residual -> d_out[output]
    gemm_bt<4><<<dim3(CC / BN, MTOK / BM), 256, 0, stream>>>(
        h1, h1, HID, HID, HID, HID, 0,
        nullptr, nullptr, outpre, nullptr, d_out, flagp);
}

// Round 10
// 424.211 us; speedup vs baseline: 1.2617x; 1.0098x over previous
//
#include <hip/hip_runtime.h>
#include <cmath>

typedef unsigned short u16;
typedef __attribute__((ext_vector_type(8))) short short8;
typedef __attribute__((ext_vector_type(4))) float f32x4;
typedef __attribute__((ext_vector_type(4))) u16 u16x4;

// ---------- bf16 helpers ----------
__device__ __forceinline__ float b2f(u16 u) {
    unsigned x = ((unsigned)u) << 16;
    return __builtin_bit_cast(float, x);
}
__device__ __forceinline__ u16 f2b(float f) {
    unsigned x = __builtin_bit_cast(unsigned, f);
    unsigned r = (x + 0x7fffu + ((x >> 16) & 1u)) >> 16;   // RNE
    return (u16)r;
}
// dtype-adaptive load (f32 flag is wave-uniform)
__device__ __forceinline__ float loadx(const void* p, size_t i, int f32) {
    return f32 ? ((const float*)p)[i] : b2f(((const u16*)p)[i]);
}
// async global->LDS, 16B per lane; LDS dest = wave-uniform base + lane*16
__device__ __forceinline__ void gl_lds16(const void* g, void* l) {
    __builtin_amdgcn_global_load_lds(
        (const __attribute__((address_space(1))) void*)g,
        (__attribute__((address_space(3))) void*)l, 16, 0, 0);
}
// fast gelu (tanh form)
__device__ __forceinline__ float gelu_f(float x) {
    float y = 0.7978845608028654f * (x + 0.044715f * x * x * x);
    float e = __expf(2.f * y);
    float t = 1.f - 2.f / (e + 1.f);    // tanh(y)
    return 0.5f * x * (1.f + t);
}

// ---------- problem constants ----------
#define BB 8
#define NN 4096
#define CC 256
#define HH 8
#define DD 32
#define HID 1024
#define MTOK (BB*NN)             // 32768 tokens
#define TOKEL ((size_t)MTOK*CC)  // 8388608 elements per [M,C] tensor
#define TOKELC 8388608

// ws offsets (bytes) — unchanged (112 MiB + 4)
#define WS_INPUT_POS 0u
#define WS_PHIQ   16777216u
#define WS_PHIK   33554432u
#define WS_V      50331648u
#define WS_XLN    67108864u
#define WS_SLN    83886080u
#define WS_OUTPRE 100663296u
#define WS_FLAG   117440512u

// ---------- bf16 weight table (device globals; zero-init BSS) ----------
#define OFF_QKVI  0u
#define OFF_QKVS  196608u
#define OFF_PROJW 393216u
#define OFF_GATEW 458752u
#define OFF_FC1W  589824u
#define OFF_FC2W  851968u
#define OFF_PROJB 1114112u
#define OFF_GATEB 1114368u
#define OFF_FC1B  1114624u
#define OFF_FC2B  1115648u
#define WTOT      1115904u
#define WCONV_BLOCKS 4359u       // WTOT/256

__device__ __attribute__((aligned(16))) u16 g_wb[WTOT];
__device__ __attribute__((aligned(16))) u16 g_inb[TOKELC];   // bf16 copy of input_
__device__ __attribute__((aligned(16))) u16 g_prevb[TOKELC]; // bf16 copy of prev_state
__device__ __attribute__((aligned(16))) u16 g_ugate[TOKELC]; // u = sigmoid(gate) bf16
__device__ __attribute__((aligned(16))) float g_kvpart[64 * 16 * 1024]; // K3 split-K partials
__device__ __attribute__((aligned(16))) u16 g_wfull[BB * CC * CC];      // W_full[b][c][h*32+d]

// =====================================================================
// K0: detect input dtype
// =====================================================================
__global__ __launch_bounds__(64) void detect_kernel(const u16* __restrict__ in0,
                                                    int* __restrict__ flag)
{
    int t = threadIdx.x;
    u16 w = in0[2 * t];
    int e = (w >> 7) & 0xFF;
    int bad = (e < 64 || e > 192) ? 1 : 0;
    unsigned long long m = __ballot(bad);
    if (t == 0) *flag = (__popcll(m) > 8) ? 1 : 0;
}

// =====================================================================
// K1: wave-per-row prep (4 rows/block, no barriers, vector loads)
//     + wconv tail blocks (weights -> bf16 table) riding the same grid
// =====================================================================
__global__ __launch_bounds__(256) void prep_kernel(
    const void* __restrict__ inp, const void* __restrict__ prev,
    const void* __restrict__ pos,
    const void* __restrict__ w1, const void* __restrict__ b1,
    const void* __restrict__ w2, const void* __restrict__ b2,
    u16* __restrict__ input_pos, u16* __restrict__ x_ln, u16* __restrict__ s_ln,
    const void* qkvi, const void* qkvs, const void* projw, const void* gatew,
    const void* fc1w, const void* fc2w, const void* projb, const void* gateb,
    const void* fc1b, const void* fc2b,
    const int* __restrict__ flagp)
{
    const int f32 = *flagp;

    // ---- wconv tail blocks ----
    if (blockIdx.x >= MTOK / 4) {
        unsigned i = (blockIdx.x - MTOK / 4) * 256 + threadIdx.x;
        if (i >= WTOT) return;
        const void* src; unsigned off;
        if      (i < OFF_QKVS)  { src = qkvi;  off = OFF_QKVI; }
        else if (i < OFF_PROJW) { src = qkvs;  off = OFF_QKVS; }
        else if (i < OFF_GATEW) { src = projw; off = OFF_PROJW; }
        else if (i < OFF_FC1W)  { src = gatew; off = OFF_GATEW; }
        else if (i < OFF_FC2W)  { src = fc1w;  off = OFF_FC1W; }
        else if (i < OFF_PROJB) { src = fc2w;  off = OFF_FC2W; }
        else if (i < OFF_GATEB) { src = projb; off = OFF_PROJB; }
        else if (i < OFF_FC1B)  { src = gateb; off = OFF_GATEB; }
        else if (i < OFF_FC2B)  { src = fc1b;  off = OFF_FC1B; }
        else                    { src = fc2b;  off = OFF_FC2B; }
        g_wb[i] = f2b(loadx(src, i - off, f32));
        return;
    }

    const int m = blockIdx.x * 4 + (threadIdx.x >> 6);
    const int lane = threadIdx.x & 63;
    const int e0 = lane * 4;
    const int n = m & (NN - 1);
    const size_t idx = (size_t)m * CC + e0;

    float inr[4], ip[4];
    if (f32) {
        f32x4 a = *(const f32x4*)((const float*)inp + idx);
        f32x4 p = *(const f32x4*)((const float*)pos + (size_t)n * CC + e0);
        #pragma unroll
        for (int r = 0; r < 4; ++r) { inr[r] = a[r]; ip[r] = a[r] + p[r]; }
    } else {
        u16x4 a = *(const u16x4*)((const u16*)inp + idx);
        u16x4 p = *(const u16x4*)((const u16*)pos + (size_t)n * CC + e0);
        #pragma unroll
        for (int r = 0; r < 4; ++r) { inr[r] = b2f(a[r]); ip[r] = inr[r] + b2f(p[r]); }
    }
    {
        u16x4 gi;
        #pragma unroll
        for (int r = 0; r < 4; ++r) gi[r] = f2b(inr[r]);
        *(u16x4*)(g_inb + idx) = gi;
    }
    float s = 0.f, s2 = 0.f;
    #pragma unroll
    for (int r = 0; r < 4; ++r) { s += ip[r]; s2 += ip[r] * ip[r]; }
    #pragma unroll
    for (int o = 1; o < 64; o <<= 1) { s += __shfl_xor(s, o, 64); s2 += __shfl_xor(s2, o, 64); }
    float mu = s * (1.f / 256.f);
    float rs = rsqrtf(s2 * (1.f / 256.f) - mu * mu + 1e-5f);
    float wv[4], bv[4];
    if (f32) {
        f32x4 w4 = *(const f32x4*)((const float*)w1 + e0);
        f32x4 b4 = *(const f32x4*)((const float*)b1 + e0);
        #pragma unroll
        for (int r = 0; r < 4; ++r) { wv[r] = w4[r]; bv[r] = b4[r]; }
    } else {
        u16x4 w4 = *(const u16x4*)((const u16*)w1 + e0);
        u16x4 b4 = *(const u16x4*)((const u16*)b1 + e0);
        #pragma unroll
        for (int r = 0; r < 4; ++r) { wv[r] = b2f(w4[r]); bv[r] = b2f(b4[r]); }
    }
    {
        u16x4 ipo, xo;
        #pragma unroll
        for (int r = 0; r < 4; ++r) {
            ipo[r] = f2b(ip[r]);
            xo[r]  = f2b((ip[r] - mu) * rs * wv[r] + bv[r]);
        }
        *(u16x4*)(input_pos + idx) = ipo;
        *(u16x4*)(x_ln + idx) = xo;
    }

    // prev pass
    float pv[4];
    if (f32) {
        f32x4 a = *(const f32x4*)((const float*)prev + idx);
        #pragma unroll
        for (int r = 0; r < 4; ++r) pv[r] = a[r];
    } else {
        u16x4 a = *(const u16x4*)((const u16*)prev + idx);
        #pragma unroll
        for (int r = 0; r < 4; ++r) pv[r] = b2f(a[r]);
    }
    {
        u16x4 gp;
        #pragma unroll
        for (int r = 0; r < 4; ++r) gp[r] = f2b(pv[r]);
        *(u16x4*)(g_prevb + idx) = gp;
    }
    s = 0.f; s2 = 0.f;
    #pragma unroll
    for (int r = 0; r < 4; ++r) { s += pv[r]; s2 += pv[r] * pv[r]; }
    #pragma unroll
    for (int o = 1; o < 64; o <<= 1) { s += __shfl_xor(s, o, 64); s2 += __shfl_xor(s2, o, 64); }
    mu = s * (1.f / 256.f);
    rs = rsqrtf(s2 * (1.f / 256.f) - mu * mu + 1e-5f);
    if (f32) {
        f32x4 w4 = *(const f32x4*)((const float*)w2 + e0);
        f32x4 b4 = *(const f32x4*)((const float*)b2 + e0);
        #pragma unroll
        for (int r = 0; r < 4; ++r) { wv[r] = w4[r]; bv[r] = b4[r]; }
    } else {
        u16x4 w4 = *(const u16x4*)((const u16*)w2 + e0);
        u16x4 b4 = *(const u16x4*)((const u16*)b2 + e0);
        #pragma unroll
        for (int r = 0; r < 4; ++r) { wv[r] = b2f(w4[r]); bv[r] = b2f(b4[r]); }
    }
    {
        u16x4 so;
        #pragma unroll
        for (int r = 0; r < 4; ++r) so[r] = f2b((pv[r] - mu) * rs * wv[r] + bv[r]);
        *(u16x4*)(s_ln + idx) = so;
    }
}

// =====================================================================
// K7': ln3_out = LN3(outpre) AND new_state = prev*(1-u) + attn_proj*u
// =====================================================================
__global__ __launch_bounds__(256) void ln3_blend_kernel(
    const u16* __restrict__ op, const void* __restrict__ w,
    const void* __restrict__ b, u16* __restrict__ out,
    const u16* __restrict__ ap, const void* __restrict__ prevraw,
    void* __restrict__ dout, const int* __restrict__ flagp)
{
    const int f32 = *flagp;
    const int m = blockIdx.x * 4 + (threadIdx.x >> 6);
    const int lane = threadIdx.x & 63;
    const int e0 = lane * 4;
    const size_t idx = (size_t)m * CC + e0;

    u16x4 x4 = *(const u16x4*)(op + idx);
    float x[4];
    #pragma unroll
    for (int r = 0; r < 4; ++r) x[r] = b2f(x4[r]);
    float s = 0.f, s2 = 0.f;
    #pragma unroll
    for (int r = 0; r < 4; ++r) { s += x[r]; s2 += x[r] * x[r]; }
    #pragma unroll
    for (int o = 1; o < 64; o <<= 1) { s += __shfl_xor(s, o, 64); s2 += __shfl_xor(s2, o, 64); }
    float mu = s * (1.f / 256.f);
    float rs = rsqrtf(s2 * (1.f / 256.f) - mu * mu + 1e-5f);
    float wv[4], bv[4];
    if (f32) {
        f32x4 w4 = *(const f32x4*)((const float*)w + e0);
        f32x4 b4 = *(const f32x4*)((const float*)b + e0);
        #pragma unroll
        for (int r = 0; r < 4; ++r) { wv[r] = w4[r]; bv[r] = b4[r]; }
    } else {
        u16x4 w4 = *(const u16x4*)((const u16*)w + e0);
        u16x4 b4 = *(const u16x4*)((const u16*)b + e0);
        #pragma unroll
        for (int r = 0; r < 4; ++r) { wv[r] = b2f(w4[r]); bv[r] = b2f(b4[r]); }
    }
    {
        u16x4 o4;
        #pragma unroll
        for (int r = 0; r < 4; ++r) o4[r] = f2b((x[r] - mu) * rs * wv[r] + bv[r]);
        *(u16x4*)(out + idx) = o4;
    }

    // new_state blend
    u16x4 a4 = *(const u16x4*)(ap + idx);
    u16x4 u4 = *(const u16x4*)(g_ugate + idx);
    if (f32) {
        f32x4 pv = *(const f32x4*)((const float*)prevraw + idx);
        f32x4 o;
        #pragma unroll
        for (int r = 0; r < 4; ++r) {
            float u = b2f(u4[r]);
            o[r] = pv[r] * (1.f - u) + b2f(a4[r]) * u;
        }
        *(f32x4*)((float*)dout + TOKEL + idx) = o;
    } else {
        u16x4 pv = *(const u16x4*)((const u16*)prevraw + idx);
        u16x4 o;
        #pragma unroll
        for (int r = 0; r < 4; ++r) {
            float u = b2f(u4[r]);
            o[r] = f2b(b2f(pv[r]) * (1.f - u) + b2f(a4[r]) * u);
        }
        *(u16x4*)((u16*)dout + TOKEL + idx) = o;
    }
}

// =====================================================================
// K3: kvpart[bh][slice][d][e] = sum_{n in slice} phik_t[bh][d][n]*v_t[bh][e][n]
// (split-K partials, plain stores; wfull_kernel reduces — no memset/atomics)
// =====================================================================
__global__ __launch_bounds__(64) void kv_mfma(
    const u16* __restrict__ phik_t, const u16* __restrict__ v_t)
{
    const int bh = blockIdx.x;
    const int k0 = blockIdx.y * 256;
    const int lane = threadIdx.x;
    const int quad = lane >> 4, lr = lane & 15;

    const u16* A = phik_t + (size_t)bh * DD * NN;
    const u16* W = v_t    + (size_t)bh * DD * NN;

    f32x4 acc[2][2];
    #pragma unroll
    for (int i = 0; i < 2; ++i)
        #pragma unroll
        for (int j = 0; j < 2; ++j) { f32x4 z = {0.f,0.f,0.f,0.f}; acc[i][j] = z; }

    for (int kk = k0; kk < k0 + 256; kk += 32) {
        short8 a0 = *(const short8*)(A + (size_t)lr * NN + kk + quad * 8);
        short8 a1 = *(const short8*)(A + (size_t)(16 + lr) * NN + kk + quad * 8);
        short8 w0 = *(const short8*)(W + (size_t)lr * NN + kk + quad * 8);
        short8 w1 = *(const short8*)(W + (size_t)(16 + lr) * NN + kk + quad * 8);
        acc[0][0] = __builtin_amdgcn_mfma_f32_16x16x32_bf16(a0, w0, acc[0][0], 0, 0, 0);
        acc[0][1] = __builtin_amdgcn_mfma_f32_16x16x32_bf16(a0, w1, acc[0][1], 0, 0, 0);
        acc[1][0] = __builtin_amdgcn_mfma_f32_16x16x32_bf16(a1, w0, acc[1][0], 0, 0, 0);
        acc[1][1] = __builtin_amdgcn_mfma_f32_16x16x32_bf16(a1, w1, acc[1][1], 0, 0, 0);
    }
    float* base = g_kvpart + ((size_t)bh * 16 + blockIdx.y) * (DD * DD);
    #pragma unroll
    for (int i = 0; i < 2; ++i)
        #pragma unroll
        for (int j = 0; j < 2; ++j)
            #pragma unroll
            for (int r = 0; r < 4; ++r)
                base[(i * 16 + quad * 4 + r) * DD + j * 16 + lr] = acc[i][j][r];
}

// =====================================================================
// K3b: W_full[b][c][h*32+d] = sum_e kv[b,h,d,e] * projw[c][h*32+e]
// (folds attn@kv@projw into one 256-wide GEMM operand; K4 deleted)
// kv reduced from g_kvpart slices. 64 blocks x 256 thr. ~34 MF total.
// =====================================================================
__global__ __launch_bounds__(256) void wfull_kernel()
{
    const int bh = blockIdx.x;            // 0..63
    const int b = bh >> 3, h = bh & 7;
    const int c = threadIdx.x;            // 0..255
    __shared__ float kvs[DD * DD];
    for (int t = threadIdx.x; t < DD * DD; t += 256) {
        float s = 0.f;
        #pragma unroll
        for (int sl = 0; sl < 16; ++sl)
            s += g_kvpart[((size_t)bh * 16 + sl) * (DD * DD) + t];
        kvs[t] = s;
    }
    __syncthreads();
    const u16* pw = g_wb + OFF_PROJW + (size_t)c * CC + h * DD;
    float pwv[DD];
    #pragma unroll
    for (int e = 0; e < DD; ++e) pwv[e] = b2f(pw[e]);
    u16* dst = g_wfull + ((size_t)b * CC + c) * CC + h * DD;
    for (int d = 0; d < DD; ++d) {
        float s = 0.f;
        #pragma unroll
        for (int e = 0; e < DD; ++e) s += pwv[e] * kvs[d * DD + e];
        dst[d] = f2b(s);
    }
}

// =====================================================================
// MFMA GEMM (R6-verified counted-vmcnt triple-buffer loop).
// MODE 0: qkv (R6 exact: bx<2 q-scatter, bx 2..5 k/v pack).
// MODE 1: FUSED proj+gate:
//   bx 0..1 -> proj: A = phiq [B,H,N,D] (k-chunk h is CONTIGUOUS 128x64B),
//              W = g_wfull[b] (kv@projw pre-contracted) -> attn_proj+outpre;
//   bx 2..3 -> gate (A=[g_inb|g_prevb], W=gatew, K=512, u -> g_ugate).
// MODE 3: fc1+gelu.  MODE 4: fc2+residual.
// =====================================================================
#define BM 128
#define BN 128
#define BK 32

template <int MODE>
__global__ __launch_bounds__(256) void gemm_bt(
    const u16* __restrict__ A1in, const u16* __restrict__ A2in,
    int lda, int ldw, int K, int Ksplit, int wcol2,
    u16* __restrict__ o0, u16* __restrict__ o1,
    const u16* __restrict__ xa, const void* __restrict__ xr,
    void* __restrict__ oraw, const int* __restrict__ flagp)
{
    __shared__ __attribute__((aligned(16))) u16 ash[3][BM * BK];
    __shared__ __attribute__((aligned(16))) u16 bsh[3][BN * BK];

    const int f32 = (MODE == 4) ? *flagp : 0;

    const u16* W1; const u16* W2; const u16* bias = nullptr;
    if (MODE == 0)      { W1 = g_wb + OFF_QKVI; W2 = g_wb + OFF_QKVS; }
    else if (MODE == 1) { W1 = W2 = nullptr;          bias = g_wb + OFF_PROJB; }
    else if (MODE == 3) { W1 = W2 = g_wb + OFF_FC1W;  bias = g_wb + OFF_FC1B; }
    else                { W1 = W2 = g_wb + OFF_FC2W;  bias = g_wb + OFF_FC2B; }

    // XCD-chunked tile swizzle (consecutive logical tiles -> same XCD L2)
    const int gx = gridDim.x;
    const int nwg = gx * (int)gridDim.y;
    const int hw = blockIdx.y * gx + blockIdx.x;
    const int qq = nwg >> 3, rr = nwg & 7;
    const int xc = hw & 7, pp = hw >> 3;
    const int nid = (xc < rr ? xc * (qq + 1) : rr * (qq + 1) + (xc - rr) * qq) + pp;
    const int bx = nid % gx, by = nid / gx;

    const bool isGate = (MODE == 1) && (bx >= 2);
    const bool swp = (MODE == 0) ? (bx < 2) : true;

    const int tid = threadIdx.x;
    const int lane = tid & 63;
    const int wv = tid >> 6;
    const int wm = wv >> 1, wn = wv & 1;
    const int quad = lane >> 4, lr = lane & 15;

    f32x4 acc[4][4];
    #pragma unroll
    for (int i = 0; i < 4; ++i)
        #pragma unroll
        for (int j = 0; j < 4; ++j) { f32x4 z = {0.f,0.f,0.f,0.f}; acc[i][j] = z; }

    const size_t arow0 = (size_t)by * BM;
    const int nbase_blk = isGate ? (bx - 2) * BN : bx * BN;
    const int ldw_eff = isGate ? 2 * CC : ldw;
    const int Keff = isGate ? 2 * CC : K;

    // staging: lane l fetches row (l&31), k-granule (l>>5)*8 [+16 on 2nd call]
    const int srow = lane & 31;
    const int sg   = (lane >> 5) << 3;     // 0 or 8 elements
    const size_t aoff = (arow0 + wv * 32 + srow) * (size_t)lda + sg;
    const size_t woff = ((size_t)nbase_blk + wv * 32 + srow) * (size_t)ldw_eff + sg;

    // proj-specific bases (MODE 1, bx<2): A = phiq [B,H,N,D], W = g_wfull[b]
    const int b_idx = (int)(arow0 >> 12);
    const size_t aq_off = ((size_t)b_idx * 8 * NN + (int)(arow0 & (NN - 1)) + wv * 32 + srow) * DD + sg;
    const size_t wf_off = (size_t)b_idx * CC * CC + ((size_t)nbase_blk + wv * 32 + srow) * CC + sg;

    auto stage = [&](int buf, int k0) {
        const u16* ga; const u16* gw;
        if (MODE == 1) {
            if (isGate) {
                const u16* As = (k0 < CC) ? g_inb : g_prevb;
                ga = As + aoff + (k0 & (CC - 1));
                gw = g_wb + OFF_GATEW + woff + k0;
            } else {
                ga = A1in + aq_off + (size_t)k0 * NN;   // k-chunk h = k0>>5
                gw = g_wfull + wf_off + k0;
            }
        } else if (MODE == 0) {
            if (k0 < Ksplit) { ga = A1in + aoff + k0;          gw = W1 + woff + k0; }
            else             { ga = A2in + aoff + (k0 - Ksplit); gw = W2 + woff + (k0 - Ksplit); }
        } else {
            ga = A1in + aoff + k0;
            gw = W1 + woff + k0;
        }
        u16* la = ash[buf] + (wv << 10);
        gl_lds16(ga, la);
        gl_lds16(ga + 16, la + 512);
        u16* lb = bsh[buf] + (wv << 10);
        gl_lds16(gw, lb);
        gl_lds16(gw + 16, lb + 512);
    };

    auto compute = [&](int buf) {
        short8 af[4], bf[4];
        #pragma unroll
        for (int i = 0; i < 4; ++i) {
            const int ra = wm * 64 + i * 16 + lr;
            af[i] = *(const short8*)(ash[buf] + ((ra >> 5) << 10) + (quad << 8) + ((ra & 31) << 3));
        }
        #pragma unroll
        for (int j = 0; j < 4; ++j) {
            const int rb = wn * 64 + j * 16 + lr;
            bf[j] = *(const short8*)(bsh[buf] + ((rb >> 5) << 10) + (quad << 8) + ((rb & 31) << 3));
        }
        if (swp) {
            #pragma unroll
            for (int i = 0; i < 4; ++i)
                #pragma unroll
                for (int j = 0; j < 4; ++j)
                    acc[i][j] = __builtin_amdgcn_mfma_f32_16x16x32_bf16(bf[j], af[i], acc[i][j], 0, 0, 0);
        } else {
            #pragma unroll
            for (int i = 0; i < 4; ++i)
                #pragma unroll
                for (int j = 0; j < 4; ++j)
                    acc[i][j] = __builtin_amdgcn_mfma_f32_16x16x32_bf16(af[i], bf[j], acc[i][j], 0, 0, 0);
        }
    };

    const int NT = Keff / BK;     // >= 8 for all modes
    stage(0, 0);
    stage(1, BK);
    for (int t = 0; t < NT; ++t) {
        if (t + 2 < NT) {
            stage((t + 2) % 3, (t + 2) * BK);
            asm volatile("s_waitcnt vmcnt(8)" ::: "memory");   // my tile-t loads done
        } else if (t + 1 < NT) {
            asm volatile("s_waitcnt vmcnt(4)" ::: "memory");
        } else {
            asm volatile("s_waitcnt vmcnt(0)" ::: "memory");
        }
        __builtin_amdgcn_s_barrier();      // tile t complete for ALL waves
        asm volatile("" ::: "memory");
        compute(t % 3);
        asm volatile("" ::: "memory");
        __builtin_amdgcn_s_barrier();      // all waves done reading tile t
    }

    const int mbase = by * BM + wm * 64;
    const int nbase = nbase_blk + wn * 64;
    constexpr int LDOUT = (MODE == 3) ? HID : CC;

    #pragma unroll
    for (int i = 0; i < 4; ++i) {
        #pragma unroll
        for (int j = 0; j < 4; ++j) {
            if (MODE == 0) {
                if (swp) {
                    // q third: row=token, cols = 4 consecutive d
                    const int m = mbase + i * 16 + lr;
                    const int b = m >> 12, n = m & (NN - 1);
                    const int c0 = nbase + j * 16 + quad * 4;  // < 256
                    const int h = c0 >> 5, d0 = c0 & 31;
                    u16x4 p;
                    #pragma unroll
                    for (int r = 0; r < 4; ++r) {
                        float v = acc[i][j][r];
                        p[r] = f2b((v > 0.f) ? (v + 1.f) : __expf(v));
                    }
                    *(u16x4*)(o0 + (((size_t)b * HH + h) * NN + n) * DD + d0) = p;
                } else {
                    // k/v thirds: unswapped; r traverses tokens -> [B,H,D,N] pack
                    const int c = nbase + j * 16 + lr;
                    const int which = c >> 8, rem = c & 255, h = rem >> 5, d = rem & 31;
                    const int m0 = mbase + i * 16 + quad * 4;
                    const int b = m0 >> 12, n0i = m0 & (NN - 1);
                    u16x4 p;
                    #pragma unroll
                    for (int r = 0; r < 4; ++r) {
                        float v = acc[i][j][r];
                        if (which == 1) v = (v > 0.f) ? (v + 1.f) : __expf(v);
                        p[r] = f2b(v);
                    }
                    u16* dst = o0 + (size_t)which * TOKEL;
                    *(u16x4*)(dst + (((size_t)b * HH + h) * DD + d) * NN + n0i) = p;
                }
            } else if (MODE == 1) {
                const int m = mbase + i * 16 + lr;
                const int c0 = nbase + j * 16 + quad * 4;
                const size_t idx0 = (size_t)m * CC + c0;
                if (isGate) {
                    // u = sigmoid(acc + gateb) -> g_ugate (bf16)
                    u16x4 b4 = *(const u16x4*)(g_wb + OFF_GATEB + c0);
                    u16x4 p;
                    #pragma unroll
                    for (int r = 0; r < 4; ++r) {
                        float u = 1.f / (1.f + __expf(-(acc[i][j][r] + b2f(b4[r]))));
                        p[r] = f2b(u);
                    }
                    *(u16x4*)(g_ugate + idx0) = p;
                } else {
                    u16x4 b4 = *(const u16x4*)(bias + c0);
                    u16x4 xa4 = *(const u16x4*)(xa + idx0);      // input_pos
                    u16x4 po, pr;
                    #pragma unroll
                    for (int r = 0; r < 4; ++r) {
                        float val = acc[i][j][r] + b2f(b4[r]);
                        po[r] = f2b(val);                      // attn_proj
                        pr[r] = f2b(b2f(xa4[r]) + val);        // outpre
                    }
                    *(u16x4*)(o0 + idx0) = po;
                    *(u16x4*)(o1 + idx0) = pr;
                }
            } else {
                // swapped: row m = mbase+i*16+lr, cols c0..c0+3
                const int m = mbase + i * 16 + lr;
                const int c0 = nbase + j * 16 + quad * 4;
                const size_t idx0 = (size_t)m * LDOUT + c0;
                float bias4[4];
                {
                    u16x4 t = *(const u16x4*)(bias + c0);
                    #pragma unroll
                    for (int r = 0; r < 4; ++r) bias4[r] = b2f(t[r]);
                }
                if (MODE == 3) {
                    u16x4 p;
                    #pragma unroll
                    for (int r = 0; r < 4; ++r)
                        p[r] = f2b(gelu_f(acc[i][j][r] + bias4[r]));
                    *(u16x4*)(o0 + idx0) = p;
                } else {
                    u16x4 xa4 = *(const u16x4*)(xa + idx0);
                    if (f32) {
                        f32x4 o;
                        #pragma unroll
                        for (int r = 0; r < 4; ++r)
                            o[r] = b2f(xa4[r]) + acc[i][j][r] + bias4[r];
                        *(f32x4*)((float*)oraw + idx0) = o;
                    } else {
                        u16x4 o;
                        #pragma unroll
                        for (int r = 0; r < 4; ++r)
                            o[r] = f2b(b2f(xa4[r]) + acc[i][j][r] + bias4[r]);
                        *(u16x4*)((u16*)oraw + idx0) = o;
                    }
                }
            }
        }
    }
}

// =====================================================================
extern "C" void kernel_launch(void* const* d_in, const int* in_sizes, int n_in,
                              void* d_out, int out_size, void* d_ws, size_t ws_size,
                              hipStream_t stream)
{
    const void* input_ = d_in[0];
    const void* prev   = d_in[1];
    const void* pos    = d_in[2];
    const void* n1w = d_in[3];  const void* n1b = d_in[4];
    const void* n2w = d_in[5];  const void* n2b = d_in[6];
    const void* n3w = d_in[7];  const void* n3b = d_in[8];
    const void* qkvi = d_in[9]; const void* qkvs = d_in[10];
    const void* projw = d_in[11]; const void* projb = d_in[12];
    const void* gatew = d_in[13]; const void* gateb = d_in[14];
    const void* fc1w = d_in[15]; const void* fc1b = d_in[16];
    const void* fc2w = d_in[17]; const void* fc2b = d_in[18];

    char* ws = (char*)d_ws;
    u16* input_pos = (u16*)(ws + WS_INPUT_POS);
    u16* phiq  = (u16*)(ws + WS_PHIQ);     // alive K2..K5'
    u16* phikt = (u16*)(ws + WS_PHIK);
    u16* vt    = (u16*)(ws + WS_V);
    u16* x_ln = (u16*)(ws + WS_XLN);
    u16* s_ln = (u16*)(ws + WS_SLN);
    u16* attn_proj = phikt;                // reuse [K5'..K7'] (phikt dead after K3)
    u16* ln3o = s_ln;                      // reuse [K7'..K8]
    u16* outpre = (u16*)(ws + WS_OUTPRE);
    u16* h1 = (u16*)(ws + WS_INPUT_POS);   // overlays 0..64MiB (dead by K8)
    int* flagp = (int*)(ws + WS_FLAG);

    // K0 dtype detect
    detect_kernel<<<1, 64, 0, stream>>>((const u16*)input_, flagp);
    // K1 prep (wave-per-row) + wconv tail blocks
    prep_kernel<<<MTOK / 4 + WCONV_BLOCKS, 256, 0, stream>>>(
        input_, prev, pos, n1w, n1b, n2w, n2b,
        input_pos, x_ln, s_ln,
        qkvi, qkvs, projw, gatew, fc1w, fc2w, projb, gateb, fc1b, fc2b, flagp);
    // K2 qkv (R6 exact): q->[B,H,N,D], k/v->[B,H,D,N]
    gemm_bt<0><<<dim3(3 * CC / BN, MTOK / BM), 256, 0, stream>>>(
        x_ln, s_ln, CC, CC, 2 * CC, CC, 0,
        phiq, nullptr, nullptr, nullptr, nullptr, flagp);
    // K3 kv einsum partials (no memset, no atomics)
    kv_mfma<<<dim3(BB * HH, 16), 64, 0, stream>>>(phikt, vt);
    // K3b reduce partials + pre-contract kv@projw -> g_wfull  (replaces K4)
    wfull_kernel<<<BB * HH, 256, 0, stream>>>();
    // K5' FUSED proj+gate: bx 0..1 proj (A=phiq, W=g_wfull), bx 2..3 gate
    gemm_bt<1><<<dim3(4, MTOK / BM), 256, 0, stream>>>(
        phiq, nullptr, CC, CC, CC, CC, 0,
        attn_proj, outpre, input_pos, nullptr, nullptr, flagp);
    // K7' LN3 + new_state blend
    ln3_blend_kernel<<<MTOK / 4, 256, 0, stream>>>(
        outpre, n3w, n3b, ln3o, attn_proj, prev, d_out, flagp);
    // K8 fc1 + gelu
    gemm_bt<3><<<dim3(HID / BN, MTOK / BM), 256, 0, stream>>>(
        ln3o, ln3o, CC, CC, CC, CC, 0,
        h1, nullptr, nullptr, nullptr, nullptr, flagp);
    // K9 fc2 + final residual -> d_out[output]
    gemm_bt<4><<<dim3(CC / BN, MTOK / BM), 256, 0, stream>>>(
        h1, h1, HID, HID, HID, HID, 0,
        nullptr, nullptr, outpre, nullptr, d_out, flagp);
}